// Round 4
// baseline (797.681 us; speedup 1.0000x reference)
//
#include <hip/hip_runtime.h>

#define HID 128
#define AROWS 173   // sum(ATOM_DIMS) = 173 (offsets end at 171, last dim = 2)

typedef __attribute__((ext_vector_type(8))) short short8;
typedef __attribute__((ext_vector_type(8))) unsigned short ushort8v;
typedef __attribute__((ext_vector_type(4))) float floatx4;
typedef __attribute__((ext_vector_type(4))) unsigned short ushort4v;

__device__ __forceinline__ unsigned short f2bf(float f) {
    unsigned u = __builtin_bit_cast(unsigned, f);
    u += 0x7FFF + ((u >> 16) & 1);           // RNE
    return (unsigned short)(u >> 16);
}
__device__ __forceinline__ float bf2f(unsigned short s) {
    unsigned u = ((unsigned)s) << 16;
    return __builtin_bit_cast(float, u);
}

// ---------------- merged fill: dis (deg accumulator) + indeg + dhist --------
__global__ void fillrd_kernel(float* __restrict__ dis, int* __restrict__ indeg,
                              int* __restrict__ dhist, int N)
{
    int i = blockIdx.x * 256 + threadIdx.x;
    if (i < N) { dis[i] = 0.f; indeg[i] = 0; }
    if (blockIdx.x == 0 && threadIdx.x < 32) dhist[threadIdx.x] = 0;
}

// ---------------- diagnostic ----------------
__global__ void diag_kernel(float* __restrict__ out, long n, float val)
{
    long i = (long)blockIdx.x * blockDim.x + threadIdx.x;
    if (i < n) out[i] = val;
}

// ---------------- merged tables: convW->bf16, linW->bf16, comb(bf16), BN fold,
//                  atom_emb->bf16 ------------------------------------------
__global__ __launch_bounds__(256) void tables_kernel(
    const float* __restrict__ conv_W, unsigned short* __restrict__ Wb,
    const float* __restrict__ lin_W, unsigned short* __restrict__ linWb,
    const float* __restrict__ bond_emb, unsigned short* __restrict__ comb,
    const float* __restrict__ gamma, const float* __restrict__ beta,
    const float* __restrict__ mean, const float* __restrict__ var,
    float* __restrict__ bnsc, float* __restrict__ bnsh,
    const float* __restrict__ atom_emb, unsigned short* __restrict__ aeb)
{
    int blk = blockIdx.x;
    int tid = threadIdx.x;
    if (blk < 64) {
        int i = blk * 256 + tid;
        Wb[i] = f2bf(conv_W[i]);
    } else if (blk < 128) {
        int i = (blk - 64) * 256 + tid;
        linWb[i] = f2bf(lin_W[i]);
    } else if (blk < 158) {
        int i = (blk - 128) * 2 + (tid >> 7);     // combo row
        int c = tid & 127;
        int a0 = i / 12, a1 = (i % 12) / 2, a2 = i % 2;
        comb[i * HID + c] = f2bf(bond_emb[a0 * HID + c] + bond_emb[(5 + a1) * HID + c]
                               + bond_emb[(11 + a2) * HID + c]);
    } else if (blk == 158) {
        if (tid < HID) {
            float sc = gamma[tid] * rsqrtf(var[tid] + 1e-5f);
            bnsc[tid] = sc;
            bnsh[tid] = beta[tid] - mean[tid] * sc;
        }
    } else {
        int i = (blk - 159) * 256 + tid;
        if (i < AROWS * HID) aeb[i] = f2bf(atom_emb[i]);
    }
}

// ---------------- merged: out-degree (row, into dis) + in-degree (col) -------
__global__ void hist_kernel(const int* __restrict__ ei, float* __restrict__ dis,
                            int* __restrict__ indeg, int E)
{
    for (int e = blockIdx.x * blockDim.x + threadIdx.x; e < E; e += gridDim.x * blockDim.x) {
        atomicAdd(&dis[ei[e]], 1.f);
        atomicAdd(&indeg[ei[E + e]], 1);
    }
}

// ---------------- merged: block-sum (scan chain) + fdeg + degree-hist --------
__global__ __launch_bounds__(256) void bsum_kernel(
    const int* __restrict__ indeg, int* __restrict__ partial,
    float* __restrict__ dis, int* __restrict__ dhist, int N)
{
    __shared__ int s[256];
    __shared__ int lh[32];
    int tid = threadIdx.x;
    if (tid < 32) lh[tid] = 0;
    int i = blockIdx.x * 256 + tid;
    int v = (i < N) ? indeg[i] : 0;
    s[tid] = v;
    if (i < N) {
        dis[i] = rsqrtf(dis[i] + 1.f);        // fdeg folded in (hist complete)
        int d = v > 31 ? 31 : v;
        atomicAdd(&lh[d], 1);
    }
    __syncthreads();
    for (int d = 128; d > 0; d >>= 1) {
        if (tid < d) s[tid] += s[tid + d];
        __syncthreads();
    }
    if (tid == 0) partial[blockIdx.x] = s[0];
    if (tid < 32 && lh[tid]) atomicAdd(&dhist[tid], lh[tid]);
}

// scan of block partials + (folded) 32-bucket degree-offset scan
__global__ __launch_bounds__(256) void scan1_kernel(
    const int* __restrict__ partial, int* __restrict__ offs,
    int* __restrict__ ptr, const int* __restrict__ dhist, int* __restrict__ dcur,
    int B, int N)
{
    __shared__ int s[256];
    __shared__ int carry_s;
    int tid = threadIdx.x;
    if (tid == 0) carry_s = 0;
    __syncthreads();
    for (int base = 0; base < B; base += 256) {
        int i = base + tid;
        int v = (i < B) ? partial[i] : 0;
        s[tid] = v;
        __syncthreads();
        for (int d = 1; d < 256; d <<= 1) {
            int t = (tid >= d) ? s[tid - d] : 0;
            __syncthreads();
            s[tid] += t;
            __syncthreads();
        }
        int carry = carry_s;
        if (i < B) offs[i] = carry + s[tid] - v;
        __syncthreads();
        if (tid == 0) carry_s = carry + s[255];
        __syncthreads();
    }
    if (tid == 0) {
        ptr[N] = carry_s;
        int sum = 0;
        for (int k = 0; k < 32; ++k) { dcur[k] = sum; sum += dhist[k]; }
    }
}

// in-place safe: cursor may alias indeg (read-before-write per element)
__global__ __launch_bounds__(256) void scan2_kernel(
    const int* __restrict__ indeg, const int* __restrict__ offs,
    int* __restrict__ ptr, int* __restrict__ cursor, int N)
{
    __shared__ int s[256];
    int tid = threadIdx.x;
    int i = blockIdx.x * 256 + tid;
    int v = (i < N) ? indeg[i] : 0;
    s[tid] = v;
    __syncthreads();
    for (int d = 1; d < 256; d <<= 1) {
        int t = (tid >= d) ? s[tid - d] : 0;
        __syncthreads();
        s[tid] += t;
        __syncthreads();
    }
    if (i < N) {
        int ex = offs[blockIdx.x] + s[tid] - v;
        ptr[i] = ex;
        cursor[i] = ex;
    }
}

// ---------------- degree-sorted permutation (counting sort, 32 buckets) ------
__global__ __launch_bounds__(256) void dperm_kernel(
    const int* __restrict__ ptr, int* __restrict__ dcur,
    int* __restrict__ perm, int N)
{
    __shared__ int lh[32];
    __shared__ int gb[32];
    int tid = threadIdx.x;
    if (tid < 32) lh[tid] = 0;
    __syncthreads();
    int n = blockIdx.x * 256 + tid;
    int rank = 0, d = 0;
    if (n < N) {
        d = ptr[n + 1] - ptr[n];
        if (d > 31) d = 31;
        rank = atomicAdd(&lh[d], 1);        // per-block rank within bucket
    }
    __syncthreads();
    if (tid < 32) gb[tid] = lh[tid] ? atomicAdd(&dcur[tid], lh[tid]) : 0;
    __syncthreads();
    if (n < N) perm[gb[d] + rank] = n;
}

// ---------------- CSR fill {row, ci|bf16(norm)<<16} + (folded) gptr ----------
__global__ void fillcsr_kernel(const int* __restrict__ ei, const int* __restrict__ attr,
                               const float* __restrict__ dis, int* __restrict__ cursor,
                               int2* __restrict__ edata, const int* __restrict__ batch,
                               int* __restrict__ gptr, int E, int N, int G)
{
    for (int e = blockIdx.x * blockDim.x + threadIdx.x; e < E; e += gridDim.x * blockDim.x) {
        int r   = ei[e];
        int col = ei[E + e];
        int pos = atomicAdd(&cursor[col], 1);
        int ci  = attr[e * 3] * 12 + attr[e * 3 + 1] * 2 + attr[e * 3 + 2];
        float nrm = dis[r] * dis[col];
        int2 ed;
        ed.x = r;
        ed.y = ci | ((int)f2bf(nrm) << 16);
        edata[pos] = ed;
    }
    for (int n = blockIdx.x * blockDim.x + threadIdx.x; n < N; n += gridDim.x * blockDim.x) {
        int b = batch[n];
        int bp = (n == 0) ? -1 : batch[n - 1];
        for (int g = bp + 1; g <= b; ++g) gptr[g] = n;
        if (n == N - 1)
            for (int g = b + 1; g <= G; ++g) gptr[g] = N;
    }
}

// ---------------- shared agg body: one node, 8 cols (16 lanes/node) ----------
template<bool FIRST>
__device__ __forceinline__ ushort8v agg_node(
    long n, int c, const int* __restrict__ ptr, const int2* __restrict__ edata,
    const unsigned short* __restrict__ comb, const float* __restrict__ dis,
    const float* __restrict__ root, const float* __restrict__ bnsc,
    const float* __restrict__ bnsh, const unsigned short* __restrict__ zb,
    const unsigned short* __restrict__ hb, float fi)
{
    ushort8v zv = *reinterpret_cast<const ushort8v*>(zb + n * HID + c);
    ushort8v hv;
    if constexpr (!FIRST) hv = *reinterpret_cast<const ushort8v*>(hb + n * HID + c);
    float di = dis[n];
    float rd = di * di;                       // 1/deg
    float acc[8];
#pragma unroll
    for (int j = 0; j < 8; ++j) acc[j] = fmaxf(bf2f(zv[j]) + root[c + j], 0.f) * rd;

    int jb = ptr[n], je = ptr[n + 1];
    int j2 = jb;
    for (; j2 + 1 < je; j2 += 2) {            // paired: 2 gathers in flight
        int2 e0 = edata[j2];
        int2 e1 = edata[j2 + 1];
        ushort8v z0 = *reinterpret_cast<const ushort8v*>(zb + (long)e0.x * HID + c);
        ushort8v z1 = *reinterpret_cast<const ushort8v*>(zb + (long)e1.x * HID + c);
        ushort8v c0 = *reinterpret_cast<const ushort8v*>(comb + (e0.y & 0xFF) * HID + c);
        ushort8v c1 = *reinterpret_cast<const ushort8v*>(comb + (e1.y & 0xFF) * HID + c);
        float n0 = bf2f((unsigned short)(((unsigned)e0.y) >> 16));
        float n1 = bf2f((unsigned short)(((unsigned)e1.y) >> 16));
#pragma unroll
        for (int j = 0; j < 8; ++j) {
            acc[j] += fmaxf(bf2f(z0[j]) + bf2f(c0[j]), 0.f) * n0;
            acc[j] += fmaxf(bf2f(z1[j]) + bf2f(c1[j]), 0.f) * n1;
        }
    }
    if (j2 < je) {
        int2 e0 = edata[j2];
        ushort8v z0 = *reinterpret_cast<const ushort8v*>(zb + (long)e0.x * HID + c);
        ushort8v c0 = *reinterpret_cast<const ushort8v*>(comb + (e0.y & 0xFF) * HID + c);
        float n0 = bf2f((unsigned short)(((unsigned)e0.y) >> 16));
#pragma unroll
        for (int j = 0; j < 8; ++j)
            acc[j] += fmaxf(bf2f(z0[j]) + bf2f(c0[j]), 0.f) * n0;
    }

    ushort8v o;
#pragma unroll
    for (int j = 0; j < 8; ++j) {
        float t = fmaxf(acc[j], 0.f) * bnsc[c + j] + bnsh[c + j];
        float h;
        if constexpr (FIRST) h = t;
        else h = fi * bf2f(hv[j]) + (1.f - fi) * t;
        o[j] = f2bf(h);
    }
    return o;
}

// ---------------- standalone agg (last iteration; nothing to fuse) -----------
template<bool FIRST>
__global__ __launch_bounds__(256) void agg_kernel(
    const int* __restrict__ perm, const int* __restrict__ ptr,
    const int2* __restrict__ edata, const unsigned short* __restrict__ comb,
    const float* __restrict__ dis, const float* __restrict__ root,
    const float* __restrict__ bnsc, const float* __restrict__ bnsh,
    const unsigned short* __restrict__ zb, unsigned short* __restrict__ hb,
    float fi, int N)
{
    long slot = (long)blockIdx.x * 16 + (threadIdx.x >> 4);
    if (slot >= N) return;
    long n = perm[slot];
    int c = (threadIdx.x & 15) * 8;
    ushort8v o = agg_node<FIRST>(n, c, ptr, edata, comb, dis, root, bnsc, bnsh,
                                 zb, hb, fi);
    *reinterpret_cast<ushort8v*>(hb + n * HID + c) = o;
}

// ---------------- fused agg + next-iter gemm: 64-row tile, full occupancy ----
// Phase A: each thread aggregates 4 degree-uniform nodes (perm-sorted) ->
// h rows into LDS + hb. Phase B: z_next = h @ W^T + b -> zout[perm rows].
// LDS 16.9 KB -> wave-slot-limited occupancy (vs round-2's 33 KB / 4 blk/CU).
template<bool FIRST>
__global__ __launch_bounds__(256) void fusedag_kernel(
    const int* __restrict__ perm, const int* __restrict__ ptr,
    const int2* __restrict__ edata, const unsigned short* __restrict__ comb,
    const float* __restrict__ dis, const float* __restrict__ root,
    const float* __restrict__ bnsc, const float* __restrict__ bnsh,
    const unsigned short* __restrict__ zin, unsigned short* __restrict__ hb,
    const unsigned short* __restrict__ Wb, const float* __restrict__ bias,
    unsigned short* __restrict__ zout, float fi, int N)
{
    __shared__ unsigned short hs[64][132];
    int tid = threadIdx.x;
    long base = (long)blockIdx.x * 64;
    int sn = tid >> 4;            // 0..15
    int cc = (tid & 15) * 8;

    // phase A: aggregate 4 node-slots (degree-uniform within block)
#pragma unroll 1
    for (int s = 0; s < 4; ++s) {
        int lr = s * 16 + sn;
        long slot = base + lr;
        ushort8v o = {0, 0, 0, 0, 0, 0, 0, 0};
        if (slot < N) {
            long n = perm[slot];
            o = agg_node<FIRST>(n, cc, ptr, edata, comb, dis, root, bnsc, bnsh,
                                zin, hb, fi);
            *reinterpret_cast<ushort8v*>(hb + n * HID + cc) = o;
        }
        *reinterpret_cast<ushort8v*>(&hs[lr][cc]) = o;
    }
    __syncthreads();

    // phase B: 4 waves x 16 rows; each wave owns its rows (read A + write C)
    int wave = tid >> 6;
    int lane = tid & 63;
    int l15 = lane & 15;
    int q = lane >> 4;
    int row0 = wave * 16;

    short8 a[4];
#pragma unroll
    for (int kb = 0; kb < 4; ++kb)
        a[kb] = *reinterpret_cast<const short8*>(&hs[row0 + l15][q * 8 + kb * 32]);

    floatx4 acc[8];
#pragma unroll
    for (int nt = 0; nt < 8; ++nt) {
        floatx4 zz = {0.f, 0.f, 0.f, 0.f};
        acc[nt] = zz;
    }
#pragma unroll
    for (int nt = 0; nt < 8; ++nt) {
        const unsigned short* bp = Wb + (nt * 16 + l15) * HID + q * 8;
#pragma unroll
        for (int kb = 0; kb < 4; ++kb) {
            short8 b = *reinterpret_cast<const short8*>(bp + kb * 32);
            acc[nt] = __builtin_amdgcn_mfma_f32_16x16x32_bf16(a[kb], b, acc[nt], 0, 0, 0);
        }
    }

    float bi[8];
#pragma unroll
    for (int nt = 0; nt < 8; ++nt) bi[nt] = bias[nt * 16 + l15];

    // C into hs (each wave writes only its own 16 rows; reads already in regs)
#pragma unroll
    for (int r = 0; r < 4; ++r) {
        int lr = row0 + q * 4 + r;
#pragma unroll
        for (int nt = 0; nt < 8; ++nt)
            hs[lr][l15 + 16 * nt] = f2bf(acc[nt][r] + bi[nt]);
    }
    __syncthreads();

    // scatter z rows to zout via perm (256B per row)
    int tr = tid >> 4;
    int tc = (tid & 15) * 8;
#pragma unroll
    for (int i = 0; i < 4; ++i) {
        int row = i * 16 + tr;
        long slot = base + row;
        if (slot < N) {
            long n = perm[slot];
            ushort8v v = *reinterpret_cast<const ushort8v*>(&hs[row][tc]);
            *reinterpret_cast<ushort8v*>(zout + n * HID + tc) = v;
        }
    }
}

// ---------------- shared MFMA epilogue (128-row): hs -> out = hs @ Wb^T + b --
__device__ __forceinline__ void gemm_from_lds(
    unsigned short (*hs)[132], const unsigned short* __restrict__ Wb,
    const float* __restrict__ bias, unsigned short* __restrict__ zb,
    long base, int N, int tid)
{
    int wave = tid >> 6;
    int lane = tid & 63;
    int l15 = lane & 15;
    int q = lane >> 4;
    int rowl0 = wave * 32;

    short8 a[2][4];
#pragma unroll
    for (int mt = 0; mt < 2; ++mt) {
        int rl = rowl0 + mt * 16 + l15;
#pragma unroll
        for (int kb = 0; kb < 4; ++kb)
            a[mt][kb] = *reinterpret_cast<const short8*>(&hs[rl][q * 8 + kb * 32]);
    }

    floatx4 acc[2][8];
#pragma unroll
    for (int mt = 0; mt < 2; ++mt)
#pragma unroll
        for (int nt = 0; nt < 8; ++nt) {
            floatx4 zz = {0.f, 0.f, 0.f, 0.f};
            acc[mt][nt] = zz;
        }

#pragma unroll
    for (int nt = 0; nt < 8; ++nt) {
        const unsigned short* bp = Wb + (nt * 16 + l15) * HID + q * 8;
#pragma unroll
        for (int kb = 0; kb < 4; ++kb) {
            short8 b = *reinterpret_cast<const short8*>(bp + kb * 32);
            acc[0][nt] = __builtin_amdgcn_mfma_f32_16x16x32_bf16(a[0][kb], b, acc[0][nt], 0, 0, 0);
            acc[1][nt] = __builtin_amdgcn_mfma_f32_16x16x32_bf16(a[1][kb], b, acc[1][nt], 0, 0, 0);
        }
    }

    float bi[8];
#pragma unroll
    for (int nt = 0; nt < 8; ++nt) bi[nt] = bias[nt * 16 + l15];

    __syncthreads();
#pragma unroll
    for (int mt = 0; mt < 2; ++mt)
#pragma unroll
        for (int r = 0; r < 4; ++r) {
            int lr = rowl0 + mt * 16 + q * 4 + r;
#pragma unroll
            for (int nt = 0; nt < 8; ++nt)
                hs[lr][l15 + 16 * nt] = f2bf(acc[mt][nt][r] + bi[nt]);
        }
    __syncthreads();

    int tr = tid >> 4;
    int tc = (tid & 15) * 8;
#pragma unroll
    for (int i = 0; i < 8; ++i) {
        int row = i * 16 + tr;
        long gr = base + row;
        if (gr < N) {
            ushort8v v = *reinterpret_cast<const ushort8v*>(&hs[row][tc]);
            *reinterpret_cast<ushort8v*>(zb + gr * HID + tc) = v;
        }
    }
}

// ---------------- fused encode + gemm#1: h0 (LDS only) -> z = h0 W^T + b -----
__global__ __launch_bounds__(256) void egemm_kernel(
    const int* __restrict__ x, const unsigned short* __restrict__ aeb,
    const unsigned short* __restrict__ Wb, const float* __restrict__ bias,
    unsigned short* __restrict__ zb, int N)
{
    __shared__ unsigned short hs[128][132];
    __shared__ int xs[128 * 9];
    int tid = threadIdx.x;
    long base = (long)blockIdx.x * 128;
    const int OFF[9] = {0, 119, 123, 135, 147, 157, 163, 169, 171};

    int nb = (N - base < 128) ? (int)(N - base) : 128;
    int cnt = nb * 9;
    for (int i = tid; i < cnt; i += 256) xs[i] = x[base * 9 + i];
    __syncthreads();

    int sn = tid >> 4;
    int cc = (tid & 15) * 8;
#pragma unroll 1
    for (int s = 0; s < 8; ++s) {
        int lr = s * 16 + sn;
        ushort8v o;
        if (lr < nb) {
            float acc[8];
#pragma unroll
            for (int j = 0; j < 8; ++j) acc[j] = 0.f;
#pragma unroll
            for (int f = 0; f < 9; ++f) {
                int idx = xs[lr * 9 + f] + OFF[f];
                ushort8v v = *reinterpret_cast<const ushort8v*>(aeb + (long)idx * HID + cc);
#pragma unroll
                for (int j = 0; j < 8; ++j) acc[j] += bf2f(v[j]);
            }
#pragma unroll
            for (int j = 0; j < 8; ++j) o[j] = f2bf(acc[j]);
        } else {
            ushort8v z8 = {0, 0, 0, 0, 0, 0, 0, 0};
            o = z8;
        }
        *reinterpret_cast<ushort8v*>(&hs[lr][cc]) = o;
    }
    __syncthreads();

    gemm_from_lds(hs, Wb, bias, zb, base, N, tid);
}

// ---------------- z = h @ W^T + b  (standalone; fallback path) ---------------
__global__ __launch_bounds__(256) void gemm_kernel(
    const unsigned short* __restrict__ hb, const unsigned short* __restrict__ Wb,
    const float* __restrict__ bias, unsigned short* __restrict__ zb, int N)
{
    __shared__ unsigned short st[128][132];
    int tid = threadIdx.x;
    int wave = tid >> 6;
    int lane = tid & 63;
    int l15 = lane & 15;
    int q = lane >> 4;
    long base = (long)blockIdx.x * 128;
    long row0 = base + wave * 32;

#pragma unroll
    for (int mt = 0; mt < 2; ++mt) {
        long rl = row0 + mt * 16 + l15;
        if (rl > (long)N - 1) rl = (long)N - 1;
        const unsigned short* ap = hb + rl * HID + q * 8;
        int lrow = wave * 32 + mt * 16 + l15;
#pragma unroll
        for (int kb = 0; kb < 4; ++kb)
            *reinterpret_cast<ushort8v*>(&st[lrow][q * 8 + kb * 32]) =
                *reinterpret_cast<const ushort8v*>(ap + kb * 32);
    }
    __syncthreads();
    gemm_from_lds(st, Wb, bias, zb, base, N, tid);
}

// ---------------- final linear via MFMA ----------------
__global__ __launch_bounds__(256) void linmm_kernel(
    const unsigned short* __restrict__ pb, const unsigned short* __restrict__ Wb,
    const float* __restrict__ bias, float* __restrict__ out, int G)
{
    int wave = threadIdx.x >> 6;
    int lane = threadIdx.x & 63;
    int l15 = lane & 15;
    int q = lane >> 4;
    long row0 = (long)blockIdx.x * 128 + wave * 32;

    short8 a[2][4];
#pragma unroll
    for (int mt = 0; mt < 2; ++mt) {
        long rl = row0 + mt * 16 + l15;
        if (rl > (long)G - 1) rl = (long)G - 1;
        const unsigned short* ap = pb + rl * HID + q * 8;
#pragma unroll
        for (int kb = 0; kb < 4; ++kb)
            a[mt][kb] = *reinterpret_cast<const short8*>(ap + kb * 32);
    }

    floatx4 acc[2][8];
#pragma unroll
    for (int mt = 0; mt < 2; ++mt)
#pragma unroll
        for (int nt = 0; nt < 8; ++nt) {
            floatx4 zz = {0.f, 0.f, 0.f, 0.f};
            acc[mt][nt] = zz;
        }

#pragma unroll
    for (int nt = 0; nt < 8; ++nt) {
        const unsigned short* bp = Wb + (nt * 16 + l15) * HID + q * 8;
#pragma unroll
        for (int kb = 0; kb < 4; ++kb) {
            short8 b = *reinterpret_cast<const short8*>(bp + kb * 32);
            acc[0][nt] = __builtin_amdgcn_mfma_f32_16x16x32_bf16(a[0][kb], b, acc[0][nt], 0, 0, 0);
            acc[1][nt] = __builtin_amdgcn_mfma_f32_16x16x32_bf16(a[1][kb], b, acc[1][nt], 0, 0, 0);
        }
    }

    float bi[8];
#pragma unroll
    for (int nt = 0; nt < 8; ++nt) bi[nt] = bias[nt * 16 + l15];

#pragma unroll
    for (int mt = 0; mt < 2; ++mt)
#pragma unroll
        for (int r = 0; r < 4; ++r) {
            long rr = row0 + mt * 16 + q * 4 + r;
            if (rr < G) {
                float* op = out + rr * HID + l15;
#pragma unroll
                for (int nt = 0; nt < 8; ++nt)
                    op[nt * 16] = acc[mt][nt][r] + bi[nt];
            }
        }
}

// ---------------- mean-pool per graph -> bf16 pooled[G][128] ----------------
__global__ __launch_bounds__(256) void pool_kernel(
    const unsigned short* __restrict__ hb, const int* __restrict__ gptr,
    unsigned short* __restrict__ pb, int G)
{
    int g = blockIdx.x;
    if (g >= G) return;
    int tid = threadIdx.x;
    int sub = tid >> 5;
    int c = (tid & 31) * 4;
    int lo = gptr[g], hi = gptr[g + 1];
    floatx4 s = {0.f, 0.f, 0.f, 0.f};
    for (int n = lo + sub; n < hi; n += 8) {
        ushort4v hv = *reinterpret_cast<const ushort4v*>(hb + (long)n * HID + c);
#pragma unroll
        for (int j = 0; j < 4; ++j) s[j] += bf2f(hv[j]);
    }
    __shared__ float ps[8][HID];
    *reinterpret_cast<floatx4*>(&ps[sub][c]) = s;
    __syncthreads();
    if (tid < HID) {
        float sum = 0.f;
#pragma unroll
        for (int k = 0; k < 8; ++k) sum += ps[k][tid];
        float cnt = (hi > lo) ? (float)(hi - lo) : 1.f;
        pb[(long)g * HID + tid] = f2bf(sum / cnt);
    }
}

extern "C" void kernel_launch(void* const* d_in, const int* in_sizes, int n_in,
                              void* d_out, int out_size, void* d_ws, size_t ws_size,
                              hipStream_t stream)
{
    const int* x          = (const int*)d_in[0];
    const int* ei         = (const int*)d_in[1];
    const int* attr       = (const int*)d_in[2];
    const int* batch      = (const int*)d_in[3];
    const float* atom_emb = (const float*)d_in[4];
    const float* bond_emb = (const float*)d_in[5];
    const float* conv_W   = (const float*)d_in[6];
    const float* conv_b   = (const float*)d_in[7];
    const float* root     = (const float*)d_in[8];
    const float* gamma    = (const float*)d_in[9];
    const float* beta     = (const float*)d_in[10];
    const float* mean     = (const float*)d_in[11];
    const float* var      = (const float*)d_in[12];
    const float* lin_W    = (const float*)d_in[13];
    const float* lin_b    = (const float*)d_in[14];
    float* out = (float*)d_out;

    const int N = in_sizes[0] / 9;
    const int E = in_sizes[1] / 2;
    const int G = out_size / HID;
    const int B = (N + 255) / 256;

    auto al = [](size_t b) { return (b + 255) & ~(size_t)255; };
    const size_t need_base =
        al((size_t)N * HID * 2) +         // hb
        al((size_t)N * HID * 2) +         // zb
        al((size_t)(N + 1) * 4) +         // ptr
        al((size_t)E * 8) +               // edata (int2)
        al((size_t)N * 4) +               // indeg (= cursor)
        al((size_t)2048 * 4) * 2 +        // partial + offs
        al((size_t)(G + 1) * 4) +         // gptr
        al((size_t)(G + 128) * HID * 2) + // pooled bf16 (dis aliases; +tail pad)
        al((size_t)60 * HID * 2) +        // comb (bf16)
        al((size_t)HID * 4) * 2 +         // bnsc + bnsh
        al((size_t)HID * HID * 2) * 2 +   // Wb + linWb
        al((size_t)AROWS * HID * 2) +     // aeb (bf16 atom table)
        al((size_t)N * 4) +               // perm
        al(32 * 4) * 2;                   // dhist + dcur
    const size_t need_fused = need_base + al((size_t)N * HID * 2);  // zb2

    if (ws_size < need_base || B > 2048) {
        float v = (B > 2048) ? 3000.f : (1000.f + (float)(ws_size >> 20));
        long n = (long)out_size;
        diag_kernel<<<(int)((n + 255) / 256), 256, 0, stream>>>(out, n, v);
        return;
    }
    const bool fused_ok = (ws_size >= need_fused);

    char* wsp = (char*)d_ws;
    size_t used = 0;
    auto alloc = [&](size_t bytes) { char* p = wsp + used; used += al(bytes); return p; };
    unsigned short* hb = (unsigned short*)alloc((size_t)N * HID * 2);
    unsigned short* zb = (unsigned short*)alloc((size_t)N * HID * 2);
    int* ptr      = (int*)alloc((size_t)(N + 1) * 4);
    int2* edata   = (int2*)alloc((size_t)E * 8);
    int* indeg    = (int*)alloc((size_t)N * 4);
    int* cursor   = indeg;                    // in-place scan (element-wise safe)
    int* partial  = (int*)alloc((size_t)2048 * 4);
    int* offs     = (int*)alloc((size_t)2048 * 4);
    int* gptr     = (int*)alloc((size_t)(G + 1) * 4);
    unsigned short* pb = (unsigned short*)alloc((size_t)(G + 128) * HID * 2);
    float* dis    = (float*)pb;               // alias: dis dead before pool writes pb
    unsigned short* comb = (unsigned short*)alloc((size_t)60 * HID * 2);
    float* bnsc   = (float*)alloc((size_t)HID * 4);
    float* bnsh   = (float*)alloc((size_t)HID * 4);
    unsigned short* Wb    = (unsigned short*)alloc((size_t)HID * HID * 2);
    unsigned short* linWb = (unsigned short*)alloc((size_t)HID * HID * 2);
    unsigned short* aeb   = (unsigned short*)alloc((size_t)AROWS * HID * 2);
    int* perm     = (int*)alloc((size_t)N * 4);
    int* dhist    = (int*)alloc(32 * 4);
    int* dcur     = (int*)alloc(32 * 4);
    unsigned short* zb2 = (unsigned short*)alloc((size_t)N * HID * 2);  // iff fused_ok

    // ---- prologue (8 launches) ----
    fillrd_kernel<<<B, 256, 0, stream>>>(dis, indeg, dhist, N);
    tables_kernel<<<246, 256, 0, stream>>>(conv_W, Wb, lin_W, linWb, bond_emb, comb,
                                           gamma, beta, mean, var, bnsc, bnsh,
                                           atom_emb, aeb);
    hist_kernel<<<1024, 256, 0, stream>>>(ei, dis, indeg, E);
    bsum_kernel<<<B, 256, 0, stream>>>(indeg, partial, dis, dhist, N);
    scan1_kernel<<<1, 256, 0, stream>>>(partial, offs, ptr, dhist, dcur, B, N);
    scan2_kernel<<<B, 256, 0, stream>>>(indeg, offs, ptr, cursor, N);
    dperm_kernel<<<B, 256, 0, stream>>>(ptr, dcur, perm, N);
    fillcsr_kernel<<<1024, 256, 0, stream>>>(ei, attr, dis, cursor, edata,
                                             batch, gptr, E, N, G);

    // ---- loop (i=1 is identity, skipped; fis = {0,2,3,4}) ----
    const int gemm_blocks  = (N + 127) / 128;
    const int fused_blocks = (N + 63) / 64;
    const int agg_blocks   = (N + 15) / 16;
    egemm_kernel<<<gemm_blocks, 256, 0, stream>>>(x, aeb, Wb, conv_b, zb, N);

    if (fused_ok) {
        fusedag_kernel<true ><<<fused_blocks, 256, 0, stream>>>(perm, ptr, edata,
                comb, dis, root, bnsc, bnsh, zb,  hb, Wb, conv_b, zb2, 0.f, N);
        fusedag_kernel<false><<<fused_blocks, 256, 0, stream>>>(perm, ptr, edata,
                comb, dis, root, bnsc, bnsh, zb2, hb, Wb, conv_b, zb,  2.f, N);
        fusedag_kernel<false><<<fused_blocks, 256, 0, stream>>>(perm, ptr, edata,
                comb, dis, root, bnsc, bnsh, zb,  hb, Wb, conv_b, zb2, 3.f, N);
        agg_kernel<false><<<agg_blocks, 256, 0, stream>>>(perm, ptr, edata, comb,
                dis, root, bnsc, bnsh, zb2, hb, 4.f, N);
    } else {
        agg_kernel<true ><<<agg_blocks, 256, 0, stream>>>(perm, ptr, edata, comb,
                dis, root, bnsc, bnsh, zb, hb, 0.f, N);
        const float fis[3] = {2.f, 3.f, 4.f};
        for (int t = 0; t < 3; ++t) {
            gemm_kernel<<<gemm_blocks, 256, 0, stream>>>(hb, Wb, conv_b, zb, N);
            agg_kernel<false><<<agg_blocks, 256, 0, stream>>>(perm, ptr, edata, comb,
                    dis, root, bnsc, bnsh, zb, hb, fis[t], N);
        }
    }

    // ---- mean-pool (bf16) + MFMA final linear (fp32 out) ----
    pool_kernel<<<G, 256, 0, stream>>>(hb, gptr, pb, G);
    linmm_kernel<<<(G + 127) / 128, 256, 0, stream>>>(pb, linWb, lin_b, out, G);
}

// Round 5
// 749.147 us; speedup vs baseline: 1.0648x; 1.0648x over previous
//
#include <hip/hip_runtime.h>

#define HID 128
#define AROWS 173   // sum(ATOM_DIMS) = 173 (offsets end at 171, last dim = 2)

typedef __attribute__((ext_vector_type(8))) short short8;
typedef __attribute__((ext_vector_type(8))) unsigned short ushort8v;
typedef __attribute__((ext_vector_type(4))) float floatx4;
typedef __attribute__((ext_vector_type(4))) unsigned short ushort4v;

__device__ __forceinline__ unsigned short f2bf(float f) {
    unsigned u = __builtin_bit_cast(unsigned, f);
    u += 0x7FFF + ((u >> 16) & 1);           // RNE
    return (unsigned short)(u >> 16);
}
__device__ __forceinline__ float bf2f(unsigned short s) {
    unsigned u = ((unsigned)s) << 16;
    return __builtin_bit_cast(float, u);
}

// ---------------- merged fill: dis (deg accumulator) + indeg + dhist --------
__global__ void fillrd_kernel(float* __restrict__ dis, int* __restrict__ indeg,
                              int* __restrict__ dhist, int N)
{
    int i = blockIdx.x * 256 + threadIdx.x;
    if (i < N) { dis[i] = 0.f; indeg[i] = 0; }
    if (blockIdx.x == 0 && threadIdx.x < 32) dhist[threadIdx.x] = 0;
}

// ---------------- diagnostic ----------------
__global__ void diag_kernel(float* __restrict__ out, long n, float val)
{
    long i = (long)blockIdx.x * blockDim.x + threadIdx.x;
    if (i < n) out[i] = val;
}

// ---------------- merged tables: convW->bf16, linW->bf16, comb(bf16), BN fold,
//                  atom_emb->bf16 ------------------------------------------
__global__ __launch_bounds__(256) void tables_kernel(
    const float* __restrict__ conv_W, unsigned short* __restrict__ Wb,
    const float* __restrict__ lin_W, unsigned short* __restrict__ linWb,
    const float* __restrict__ bond_emb, unsigned short* __restrict__ comb,
    const float* __restrict__ gamma, const float* __restrict__ beta,
    const float* __restrict__ mean, const float* __restrict__ var,
    float* __restrict__ bnsc, float* __restrict__ bnsh,
    const float* __restrict__ atom_emb, unsigned short* __restrict__ aeb)
{
    int blk = blockIdx.x;
    int tid = threadIdx.x;
    if (blk < 64) {
        int i = blk * 256 + tid;
        Wb[i] = f2bf(conv_W[i]);
    } else if (blk < 128) {
        int i = (blk - 64) * 256 + tid;
        linWb[i] = f2bf(lin_W[i]);
    } else if (blk < 158) {
        int i = (blk - 128) * 2 + (tid >> 7);     // combo row
        int c = tid & 127;
        int a0 = i / 12, a1 = (i % 12) / 2, a2 = i % 2;
        comb[i * HID + c] = f2bf(bond_emb[a0 * HID + c] + bond_emb[(5 + a1) * HID + c]
                               + bond_emb[(11 + a2) * HID + c]);
    } else if (blk == 158) {
        if (tid < HID) {
            float sc = gamma[tid] * rsqrtf(var[tid] + 1e-5f);
            bnsc[tid] = sc;
            bnsh[tid] = beta[tid] - mean[tid] * sc;
        }
    } else {
        int i = (blk - 159) * 256 + tid;
        if (i < AROWS * HID) aeb[i] = f2bf(atom_emb[i]);
    }
}

// ---------------- merged: out-degree (row, into dis) + in-degree (col) -------
__global__ void hist_kernel(const int* __restrict__ ei, float* __restrict__ dis,
                            int* __restrict__ indeg, int E)
{
    for (int e = blockIdx.x * blockDim.x + threadIdx.x; e < E; e += gridDim.x * blockDim.x) {
        atomicAdd(&dis[ei[e]], 1.f);
        atomicAdd(&indeg[ei[E + e]], 1);
    }
}

// ---------------- fdeg (dis -> deg^-0.5) + degree histogram ------------------
__global__ __launch_bounds__(256) void fdh_kernel(
    float* __restrict__ dis, const int* __restrict__ indeg,
    int* __restrict__ dhist, int N)
{
    __shared__ int lh[32];
    int tid = threadIdx.x;
    if (tid < 32) lh[tid] = 0;
    __syncthreads();
    int i = blockIdx.x * 256 + tid;
    if (i < N) {
        dis[i] = rsqrtf(dis[i] + 1.f);
        int d = indeg[i]; if (d > 31) d = 31;
        atomicAdd(&lh[d], 1);
    }
    __syncthreads();
    if (tid < 32 && lh[tid]) atomicAdd(&dhist[tid], lh[tid]);
}

__global__ void dscan_kernel(const int* __restrict__ dhist, int* __restrict__ dcur)
{
    if (threadIdx.x == 0) {
        int s = 0;
        for (int k = 0; k < 32; ++k) { dcur[k] = s; s += dhist[k]; }
    }
}

// ---------------- degree-sorted permutation + inverse ------------------------
__global__ __launch_bounds__(256) void dperm_kernel(
    const int* __restrict__ indeg, int* __restrict__ dcur,
    int* __restrict__ perm, int* __restrict__ invperm, int N)
{
    __shared__ int lh[32];
    __shared__ int gb[32];
    int tid = threadIdx.x;
    if (tid < 32) lh[tid] = 0;
    __syncthreads();
    int n = blockIdx.x * 256 + tid;
    int rank = 0, d = 0;
    if (n < N) {
        d = indeg[n]; if (d > 31) d = 31;
        rank = atomicAdd(&lh[d], 1);        // per-block rank within bucket
    }
    __syncthreads();
    if (tid < 32) gb[tid] = lh[tid] ? atomicAdd(&dcur[tid], lh[tid]) : 0;
    __syncthreads();
    if (n < N) {
        int slot = gb[d] + rank;
        perm[slot] = n;
        invperm[n] = slot;
    }
}

// ---------------- slot-order CSR scan chain ----------------------------------
// sptr[slot] = exclusive scan of indeg[perm[slot]]; edata2 grouped by slot so
// each agg block (16 consecutive slots) owns ONE contiguous edge range.
__global__ __launch_bounds__(256) void sbsum_kernel(
    const int* __restrict__ indeg, const int* __restrict__ perm,
    int* __restrict__ partial, int N)
{
    __shared__ int s[256];
    int tid = threadIdx.x;
    int i = blockIdx.x * 256 + tid;
    s[tid] = (i < N) ? indeg[perm[i]] : 0;
    __syncthreads();
    for (int d = 128; d > 0; d >>= 1) {
        if (tid < d) s[tid] += s[tid + d];
        __syncthreads();
    }
    if (tid == 0) partial[blockIdx.x] = s[0];
}

__global__ __launch_bounds__(256) void sscan1_kernel(
    const int* __restrict__ partial, int* __restrict__ offs,
    int* __restrict__ sptr, int B, int N)
{
    __shared__ int s[256];
    __shared__ int carry_s;
    int tid = threadIdx.x;
    if (tid == 0) carry_s = 0;
    __syncthreads();
    for (int base = 0; base < B; base += 256) {
        int i = base + tid;
        int v = (i < B) ? partial[i] : 0;
        s[tid] = v;
        __syncthreads();
        for (int d = 1; d < 256; d <<= 1) {
            int t = (tid >= d) ? s[tid - d] : 0;
            __syncthreads();
            s[tid] += t;
            __syncthreads();
        }
        int carry = carry_s;
        if (i < B) offs[i] = carry + s[tid] - v;
        __syncthreads();
        if (tid == 0) carry_s = carry + s[255];
        __syncthreads();
    }
    if (tid == 0) sptr[N] = carry_s;
}

__global__ __launch_bounds__(256) void sscan2_kernel(
    const int* __restrict__ indeg, const int* __restrict__ perm,
    const int* __restrict__ offs, int* __restrict__ sptr,
    int* __restrict__ scursor, int N)
{
    __shared__ int s[256];
    int tid = threadIdx.x;
    int i = blockIdx.x * 256 + tid;
    int v = (i < N) ? indeg[perm[i]] : 0;
    s[tid] = v;
    __syncthreads();
    for (int d = 1; d < 256; d <<= 1) {
        int t = (tid >= d) ? s[tid - d] : 0;
        __syncthreads();
        s[tid] += t;
        __syncthreads();
    }
    if (i < N) {
        int ex = offs[blockIdx.x] + s[tid] - v;
        sptr[i] = ex;
        scursor[i] = ex;
    }
}

// ---------------- CSR fill (slot order) {row, ci|bf16(norm)<<16} + gptr ------
__global__ void fillcsr_kernel(const int* __restrict__ ei, const int* __restrict__ attr,
                               const float* __restrict__ dis,
                               const int* __restrict__ invperm,
                               int* __restrict__ scursor,
                               int2* __restrict__ edata, const int* __restrict__ batch,
                               int* __restrict__ gptr, int E, int N, int G)
{
    for (int e = blockIdx.x * blockDim.x + threadIdx.x; e < E; e += gridDim.x * blockDim.x) {
        int r   = ei[e];
        int col = ei[E + e];
        int slot = invperm[col];
        int pos = atomicAdd(&scursor[slot], 1);
        int ci  = attr[e * 3] * 12 + attr[e * 3 + 1] * 2 + attr[e * 3 + 2];
        float nrm = dis[r] * dis[col];
        int2 ed;
        ed.x = r;
        ed.y = ci | ((int)f2bf(nrm) << 16);
        edata[pos] = ed;
    }
    for (int n = blockIdx.x * blockDim.x + threadIdx.x; n < N; n += gridDim.x * blockDim.x) {
        int b = batch[n];
        int bp = (n == 0) ? -1 : batch[n - 1];
        for (int g = bp + 1; g <= b; ++g) gptr[g] = n;
        if (n == N - 1)
            for (int g = b + 1; g <= G; ++g) gptr[g] = N;
    }
}

// ---------------- agg: slot-ordered CSR, degree-uniform blocks ---------------
// chain: perm/sptr (coalesced) -> edata2 (sequential per block) -> z (random).
template<bool FIRST>
__global__ __launch_bounds__(256) void agg_kernel(
    const int* __restrict__ perm, const int* __restrict__ sptr,
    const int2* __restrict__ edata, const unsigned short* __restrict__ comb,
    const float* __restrict__ dis, const float* __restrict__ root,
    const float* __restrict__ bnsc, const float* __restrict__ bnsh,
    const unsigned short* __restrict__ zb, unsigned short* __restrict__ hb,
    float fi, int N)
{
    long slot = (long)blockIdx.x * 16 + (threadIdx.x >> 4);
    if (slot >= N) return;
    long n = perm[slot];
    int c = (threadIdx.x & 15) * 8;

    int jb = sptr[slot], je = sptr[slot + 1];

    ushort8v zv = *reinterpret_cast<const ushort8v*>(zb + n * HID + c);
    ushort8v hv;
    if constexpr (!FIRST) hv = *reinterpret_cast<const ushort8v*>(hb + n * HID + c);
    float di = dis[n];
    float rd = di * di;                       // 1/deg
    float acc[8];
#pragma unroll
    for (int j = 0; j < 8; ++j) acc[j] = fmaxf(bf2f(zv[j]) + root[c + j], 0.f) * rd;

    int j2 = jb;
    for (; j2 + 1 < je; j2 += 2) {            // paired: 2 gathers in flight
        int2 e0 = edata[j2];
        int2 e1 = edata[j2 + 1];
        ushort8v z0 = *reinterpret_cast<const ushort8v*>(zb + (long)e0.x * HID + c);
        ushort8v z1 = *reinterpret_cast<const ushort8v*>(zb + (long)e1.x * HID + c);
        ushort8v c0 = *reinterpret_cast<const ushort8v*>(comb + (e0.y & 0xFF) * HID + c);
        ushort8v c1 = *reinterpret_cast<const ushort8v*>(comb + (e1.y & 0xFF) * HID + c);
        float n0 = bf2f((unsigned short)(((unsigned)e0.y) >> 16));
        float n1 = bf2f((unsigned short)(((unsigned)e1.y) >> 16));
#pragma unroll
        for (int j = 0; j < 8; ++j) {
            acc[j] += fmaxf(bf2f(z0[j]) + bf2f(c0[j]), 0.f) * n0;
            acc[j] += fmaxf(bf2f(z1[j]) + bf2f(c1[j]), 0.f) * n1;
        }
    }
    if (j2 < je) {
        int2 e0 = edata[j2];
        ushort8v z0 = *reinterpret_cast<const ushort8v*>(zb + (long)e0.x * HID + c);
        ushort8v c0 = *reinterpret_cast<const ushort8v*>(comb + (e0.y & 0xFF) * HID + c);
        float n0 = bf2f((unsigned short)(((unsigned)e0.y) >> 16));
#pragma unroll
        for (int j = 0; j < 8; ++j)
            acc[j] += fmaxf(bf2f(z0[j]) + bf2f(c0[j]), 0.f) * n0;
    }

    ushort8v o;
#pragma unroll
    for (int j = 0; j < 8; ++j) {
        float t = fmaxf(acc[j], 0.f) * bnsc[c + j] + bnsh[c + j];
        float h;
        if constexpr (FIRST) h = t;
        else h = fi * bf2f(hv[j]) + (1.f - fi) * t;
        o[j] = f2bf(h);
    }
    *reinterpret_cast<ushort8v*>(hb + n * HID + c) = o;
}

// ---------------- shared MFMA epilogue (128-row): hs -> out = hs @ Wb^T + b --
__device__ __forceinline__ void gemm_from_lds(
    unsigned short (*hs)[132], const unsigned short* __restrict__ Wb,
    const float* __restrict__ bias, unsigned short* __restrict__ zb,
    long base, int N, int tid)
{
    int wave = tid >> 6;
    int lane = tid & 63;
    int l15 = lane & 15;
    int q = lane >> 4;
    int rowl0 = wave * 32;

    short8 a[2][4];
#pragma unroll
    for (int mt = 0; mt < 2; ++mt) {
        int rl = rowl0 + mt * 16 + l15;
#pragma unroll
        for (int kb = 0; kb < 4; ++kb)
            a[mt][kb] = *reinterpret_cast<const short8*>(&hs[rl][q * 8 + kb * 32]);
    }

    floatx4 acc[2][8];
#pragma unroll
    for (int mt = 0; mt < 2; ++mt)
#pragma unroll
        for (int nt = 0; nt < 8; ++nt) {
            floatx4 zz = {0.f, 0.f, 0.f, 0.f};
            acc[mt][nt] = zz;
        }

#pragma unroll
    for (int nt = 0; nt < 8; ++nt) {
        const unsigned short* bp = Wb + (nt * 16 + l15) * HID + q * 8;
#pragma unroll
        for (int kb = 0; kb < 4; ++kb) {
            short8 b = *reinterpret_cast<const short8*>(bp + kb * 32);
            acc[0][nt] = __builtin_amdgcn_mfma_f32_16x16x32_bf16(a[0][kb], b, acc[0][nt], 0, 0, 0);
            acc[1][nt] = __builtin_amdgcn_mfma_f32_16x16x32_bf16(a[1][kb], b, acc[1][nt], 0, 0, 0);
        }
    }

    float bi[8];
#pragma unroll
    for (int nt = 0; nt < 8; ++nt) bi[nt] = bias[nt * 16 + l15];

    __syncthreads();
#pragma unroll
    for (int mt = 0; mt < 2; ++mt)
#pragma unroll
        for (int r = 0; r < 4; ++r) {
            int lr = rowl0 + mt * 16 + q * 4 + r;
#pragma unroll
            for (int nt = 0; nt < 8; ++nt)
                hs[lr][l15 + 16 * nt] = f2bf(acc[mt][nt][r] + bi[nt]);
        }
    __syncthreads();

    int tr = tid >> 4;
    int tc = (tid & 15) * 8;
#pragma unroll
    for (int i = 0; i < 8; ++i) {
        int row = i * 16 + tr;
        long gr = base + row;
        if (gr < N) {
            ushort8v v = *reinterpret_cast<const ushort8v*>(&hs[row][tc]);
            *reinterpret_cast<ushort8v*>(zb + gr * HID + tc) = v;
        }
    }
}

// ---------------- fused encode + gemm#1, 64-row tile (19.2 KB LDS, 8 blk/CU) -
__global__ __launch_bounds__(256) void egemm_kernel(
    const int* __restrict__ x, const unsigned short* __restrict__ aeb,
    const unsigned short* __restrict__ Wb, const float* __restrict__ bias,
    unsigned short* __restrict__ zb, int N)
{
    __shared__ unsigned short hs[64][132];
    __shared__ int xs[64 * 9];
    int tid = threadIdx.x;
    long base = (long)blockIdx.x * 64;
    const int OFF[9] = {0, 119, 123, 135, 147, 157, 163, 169, 171};

    int nb = (N - base < 64) ? (int)(N - base) : 64;
    int cnt = nb * 9;
    for (int i = tid; i < cnt; i += 256) xs[i] = x[base * 9 + i];
    __syncthreads();

    // phase A: embedding sums (bf16 table; x from LDS broadcast)
    int sn = tid >> 4;
    int cc = (tid & 15) * 8;
#pragma unroll 1
    for (int s = 0; s < 4; ++s) {
        int lr = s * 16 + sn;
        ushort8v o;
        if (lr < nb) {
            float acc[8];
#pragma unroll
            for (int j = 0; j < 8; ++j) acc[j] = 0.f;
#pragma unroll
            for (int f = 0; f < 9; ++f) {
                int idx = xs[lr * 9 + f] + OFF[f];
                ushort8v v = *reinterpret_cast<const ushort8v*>(aeb + (long)idx * HID + cc);
#pragma unroll
                for (int j = 0; j < 8; ++j) acc[j] += bf2f(v[j]);
            }
#pragma unroll
            for (int j = 0; j < 8; ++j) o[j] = f2bf(acc[j]);
        } else {
            ushort8v z8 = {0, 0, 0, 0, 0, 0, 0, 0};
            o = z8;
        }
        *reinterpret_cast<ushort8v*>(&hs[lr][cc]) = o;
    }
    __syncthreads();

    // phase B: 4 waves x 16 rows (validated wave mapping from round-4 phase B)
    int wave = tid >> 6;
    int lane = tid & 63;
    int l15 = lane & 15;
    int q = lane >> 4;
    int row0 = wave * 16;

    short8 a[4];
#pragma unroll
    for (int kb = 0; kb < 4; ++kb)
        a[kb] = *reinterpret_cast<const short8*>(&hs[row0 + l15][q * 8 + kb * 32]);

    floatx4 acc[8];
#pragma unroll
    for (int nt = 0; nt < 8; ++nt) {
        floatx4 zz = {0.f, 0.f, 0.f, 0.f};
        acc[nt] = zz;
    }
#pragma unroll
    for (int nt = 0; nt < 8; ++nt) {
        const unsigned short* bp = Wb + (nt * 16 + l15) * HID + q * 8;
#pragma unroll
        for (int kb = 0; kb < 4; ++kb) {
            short8 b = *reinterpret_cast<const short8*>(bp + kb * 32);
            acc[nt] = __builtin_amdgcn_mfma_f32_16x16x32_bf16(a[kb], b, acc[nt], 0, 0, 0);
        }
    }

    float bi[8];
#pragma unroll
    for (int nt = 0; nt < 8; ++nt) bi[nt] = bias[nt * 16 + l15];

#pragma unroll
    for (int r = 0; r < 4; ++r) {
        int lr = row0 + q * 4 + r;
#pragma unroll
        for (int nt = 0; nt < 8; ++nt)
            hs[lr][l15 + 16 * nt] = f2bf(acc[nt][r] + bi[nt]);
    }
    __syncthreads();

    int tr = tid >> 4;
    int tc = (tid & 15) * 8;
#pragma unroll
    for (int i = 0; i < 4; ++i) {
        int row = i * 16 + tr;
        long gr = base + row;
        if (gr < N) {
            ushort8v v = *reinterpret_cast<const ushort8v*>(&hs[row][tc]);
            *reinterpret_cast<ushort8v*>(zb + gr * HID + tc) = v;
        }
    }
}

// ---------------- z = h @ W^T + b  (standalone) ----------------
__global__ __launch_bounds__(256) void gemm_kernel(
    const unsigned short* __restrict__ hb, const unsigned short* __restrict__ Wb,
    const float* __restrict__ bias, unsigned short* __restrict__ zb, int N)
{
    __shared__ unsigned short st[128][132];
    int tid = threadIdx.x;
    int wave = tid >> 6;
    int lane = tid & 63;
    int l15 = lane & 15;
    int q = lane >> 4;
    long base = (long)blockIdx.x * 128;
    long row0 = base + wave * 32;

#pragma unroll
    for (int mt = 0; mt < 2; ++mt) {
        long rl = row0 + mt * 16 + l15;
        if (rl > (long)N - 1) rl = (long)N - 1;
        const unsigned short* ap = hb + rl * HID + q * 8;
        int lrow = wave * 32 + mt * 16 + l15;
#pragma unroll
        for (int kb = 0; kb < 4; ++kb)
            *reinterpret_cast<ushort8v*>(&st[lrow][q * 8 + kb * 32]) =
                *reinterpret_cast<const ushort8v*>(ap + kb * 32);
    }
    __syncthreads();
    gemm_from_lds(st, Wb, bias, zb, base, N, tid);
}

// ---------------- final linear via MFMA ----------------
__global__ __launch_bounds__(256) void linmm_kernel(
    const unsigned short* __restrict__ pb, const unsigned short* __restrict__ Wb,
    const float* __restrict__ bias, float* __restrict__ out, int G)
{
    int wave = threadIdx.x >> 6;
    int lane = threadIdx.x & 63;
    int l15 = lane & 15;
    int q = lane >> 4;
    long row0 = (long)blockIdx.x * 128 + wave * 32;

    short8 a[2][4];
#pragma unroll
    for (int mt = 0; mt < 2; ++mt) {
        long rl = row0 + mt * 16 + l15;
        if (rl > (long)G - 1) rl = (long)G - 1;
        const unsigned short* ap = pb + rl * HID + q * 8;
#pragma unroll
        for (int kb = 0; kb < 4; ++kb)
            a[mt][kb] = *reinterpret_cast<const short8*>(ap + kb * 32);
    }

    floatx4 acc[2][8];
#pragma unroll
    for (int mt = 0; mt < 2; ++mt)
#pragma unroll
        for (int nt = 0; nt < 8; ++nt) {
            floatx4 zz = {0.f, 0.f, 0.f, 0.f};
            acc[mt][nt] = zz;
        }

#pragma unroll
    for (int nt = 0; nt < 8; ++nt) {
        const unsigned short* bp = Wb + (nt * 16 + l15) * HID + q * 8;
#pragma unroll
        for (int kb = 0; kb < 4; ++kb) {
            short8 b = *reinterpret_cast<const short8*>(bp + kb * 32);
            acc[0][nt] = __builtin_amdgcn_mfma_f32_16x16x32_bf16(a[0][kb], b, acc[0][nt], 0, 0, 0);
            acc[1][nt] = __builtin_amdgcn_mfma_f32_16x16x32_bf16(a[1][kb], b, acc[1][nt], 0, 0, 0);
        }
    }

    float bi[8];
#pragma unroll
    for (int nt = 0; nt < 8; ++nt) bi[nt] = bias[nt * 16 + l15];

#pragma unroll
    for (int mt = 0; mt < 2; ++mt)
#pragma unroll
        for (int r = 0; r < 4; ++r) {
            long rr = row0 + mt * 16 + q * 4 + r;
            if (rr < G) {
                float* op = out + rr * HID + l15;
#pragma unroll
                for (int nt = 0; nt < 8; ++nt)
                    op[nt * 16] = acc[mt][nt][r] + bi[nt];
            }
        }
}

// ---------------- mean-pool per graph -> bf16 pooled[G][128] ----------------
__global__ __launch_bounds__(256) void pool_kernel(
    const unsigned short* __restrict__ hb, const int* __restrict__ gptr,
    unsigned short* __restrict__ pb, int G)
{
    int g = blockIdx.x;
    if (g >= G) return;
    int tid = threadIdx.x;
    int sub = tid >> 5;
    int c = (tid & 31) * 4;
    int lo = gptr[g], hi = gptr[g + 1];
    floatx4 s = {0.f, 0.f, 0.f, 0.f};
    for (int n = lo + sub; n < hi; n += 8) {
        ushort4v hv = *reinterpret_cast<const ushort4v*>(hb + (long)n * HID + c);
#pragma unroll
        for (int j = 0; j < 4; ++j) s[j] += bf2f(hv[j]);
    }
    __shared__ float ps[8][HID];
    *reinterpret_cast<floatx4*>(&ps[sub][c]) = s;
    __syncthreads();
    if (tid < HID) {
        float sum = 0.f;
#pragma unroll
        for (int k = 0; k < 8; ++k) sum += ps[k][tid];
        float cnt = (hi > lo) ? (float)(hi - lo) : 1.f;
        pb[(long)g * HID + tid] = f2bf(sum / cnt);
    }
}

extern "C" void kernel_launch(void* const* d_in, const int* in_sizes, int n_in,
                              void* d_out, int out_size, void* d_ws, size_t ws_size,
                              hipStream_t stream)
{
    const int* x          = (const int*)d_in[0];
    const int* ei         = (const int*)d_in[1];
    const int* attr       = (const int*)d_in[2];
    const int* batch      = (const int*)d_in[3];
    const float* atom_emb = (const float*)d_in[4];
    const float* bond_emb = (const float*)d_in[5];
    const float* conv_W   = (const float*)d_in[6];
    const float* conv_b   = (const float*)d_in[7];
    const float* root     = (const float*)d_in[8];
    const float* gamma    = (const float*)d_in[9];
    const float* beta     = (const float*)d_in[10];
    const float* mean     = (const float*)d_in[11];
    const float* var      = (const float*)d_in[12];
    const float* lin_W    = (const float*)d_in[13];
    const float* lin_b    = (const float*)d_in[14];
    float* out = (float*)d_out;

    const int N = in_sizes[0] / 9;
    const int E = in_sizes[1] / 2;
    const int G = out_size / HID;
    const int B = (N + 255) / 256;

    auto al = [](size_t b) { return (b + 255) & ~(size_t)255; };
    const size_t need =
        al((size_t)N * HID * 2) +         // hb
        al((size_t)N * HID * 2) +         // zb
        al((size_t)(N + 1) * 4) +         // sptr
        al((size_t)E * 8) +               // edata (int2)
        al((size_t)N * 4) +               // indeg
        al((size_t)N * 4) +               // perm
        al((size_t)N * 4) +               // invperm
        al((size_t)N * 4) +               // scursor
        al((size_t)2048 * 4) * 2 +        // partial + offs
        al((size_t)(G + 1) * 4) +         // gptr
        al((size_t)(G + 128) * HID * 2) + // pooled bf16 (dis aliases; +tail pad)
        al((size_t)60 * HID * 2) +        // comb (bf16)
        al((size_t)HID * 4) * 2 +         // bnsc + bnsh
        al((size_t)HID * HID * 2) * 2 +   // Wb + linWb
        al((size_t)AROWS * HID * 2) +     // aeb (bf16 atom table)
        al(32 * 4) * 2;                   // dhist + dcur

    if (ws_size < need || B > 2048) {
        float v = (B > 2048) ? 3000.f : (1000.f + (float)(ws_size >> 20));
        long n = (long)out_size;
        diag_kernel<<<(int)((n + 255) / 256), 256, 0, stream>>>(out, n, v);
        return;
    }

    char* wsp = (char*)d_ws;
    size_t used = 0;
    auto alloc = [&](size_t bytes) { char* p = wsp + used; used += al(bytes); return p; };
    unsigned short* hb = (unsigned short*)alloc((size_t)N * HID * 2);
    unsigned short* zb = (unsigned short*)alloc((size_t)N * HID * 2);
    int* sptr     = (int*)alloc((size_t)(N + 1) * 4);
    int2* edata   = (int2*)alloc((size_t)E * 8);
    int* indeg    = (int*)alloc((size_t)N * 4);
    int* perm     = (int*)alloc((size_t)N * 4);
    int* invperm  = (int*)alloc((size_t)N * 4);
    int* scursor  = (int*)alloc((size_t)N * 4);
    int* partial  = (int*)alloc((size_t)2048 * 4);
    int* offs     = (int*)alloc((size_t)2048 * 4);
    int* gptr     = (int*)alloc((size_t)(G + 1) * 4);
    unsigned short* pb = (unsigned short*)alloc((size_t)(G + 128) * HID * 2);
    float* dis    = (float*)pb;               // alias: dis dead before pool writes pb
    unsigned short* comb = (unsigned short*)alloc((size_t)60 * HID * 2);
    float* bnsc   = (float*)alloc((size_t)HID * 4);
    float* bnsh   = (float*)alloc((size_t)HID * 4);
    unsigned short* Wb    = (unsigned short*)alloc((size_t)HID * HID * 2);
    unsigned short* linWb = (unsigned short*)alloc((size_t)HID * HID * 2);
    unsigned short* aeb   = (unsigned short*)alloc((size_t)AROWS * HID * 2);
    int* dhist    = (int*)alloc(32 * 4);
    int* dcur     = (int*)alloc(32 * 4);

    // ---- prologue (10 launches) ----
    fillrd_kernel<<<B, 256, 0, stream>>>(dis, indeg, dhist, N);
    tables_kernel<<<246, 256, 0, stream>>>(conv_W, Wb, lin_W, linWb, bond_emb, comb,
                                           gamma, beta, mean, var, bnsc, bnsh,
                                           atom_emb, aeb);
    hist_kernel<<<1024, 256, 0, stream>>>(ei, dis, indeg, E);
    fdh_kernel<<<B, 256, 0, stream>>>(dis, indeg, dhist, N);
    dscan_kernel<<<1, 64, 0, stream>>>(dhist, dcur);
    dperm_kernel<<<B, 256, 0, stream>>>(indeg, dcur, perm, invperm, N);
    sbsum_kernel<<<B, 256, 0, stream>>>(indeg, perm, partial, N);
    sscan1_kernel<<<1, 256, 0, stream>>>(partial, offs, sptr, B, N);
    sscan2_kernel<<<B, 256, 0, stream>>>(indeg, perm, offs, sptr, scursor, N);
    fillcsr_kernel<<<1024, 256, 0, stream>>>(ei, attr, dis, invperm, scursor, edata,
                                             batch, gptr, E, N, G);

    // ---- loop (i=1 is identity, skipped; fis = {0,2,3,4}) ----
    const int egemm_blocks = (N + 63) / 64;
    const int gemm_blocks  = (N + 127) / 128;
    const int agg_blocks   = (N + 15) / 16;
    egemm_kernel<<<egemm_blocks, 256, 0, stream>>>(x, aeb, Wb, conv_b, zb, N);
    agg_kernel<true ><<<agg_blocks, 256, 0, stream>>>(perm, sptr, edata, comb, dis,
            root, bnsc, bnsh, zb, hb, 0.f, N);
    const float fis[3] = {2.f, 3.f, 4.f};
    for (int t = 0; t < 3; ++t) {
        gemm_kernel<<<gemm_blocks, 256, 0, stream>>>(hb, Wb, conv_b, zb, N);
        agg_kernel<false><<<agg_blocks, 256, 0, stream>>>(perm, sptr, edata, comb, dis,
                root, bnsc, bnsh, zb, hb, fis[t], N);
    }

    // ---- mean-pool (bf16) + MFMA final linear (fp32 out) ----
    pool_kernel<<<G, 256, 0, stream>>>(hb, gptr, pb, G);
    linmm_kernel<<<(G + 127) / 128, 256, 0, stream>>>(pb, linWb, lin_b, out, G);
}

// Round 6
// 726.615 us; speedup vs baseline: 1.0978x; 1.0310x over previous
//
#include <hip/hip_runtime.h>

#define HID 128
#define AROWS 173   // sum(ATOM_DIMS) = 173 (offsets end at 171, last dim = 2)

typedef __attribute__((ext_vector_type(8))) short short8;
typedef __attribute__((ext_vector_type(8))) unsigned short ushort8v;
typedef __attribute__((ext_vector_type(4))) float floatx4;
typedef __attribute__((ext_vector_type(4))) unsigned short ushort4v;

__device__ __forceinline__ unsigned short f2bf(float f) {
    unsigned u = __builtin_bit_cast(unsigned, f);
    u += 0x7FFF + ((u >> 16) & 1);           // RNE
    return (unsigned short)(u >> 16);
}
__device__ __forceinline__ float bf2f(unsigned short s) {
    unsigned u = ((unsigned)s) << 16;
    return __builtin_bit_cast(float, u);
}

// ---------------- merged fill: dis (deg accumulator) + indeg + dhist --------
__global__ void fillrd_kernel(float* __restrict__ dis, int* __restrict__ indeg,
                              int* __restrict__ dhist, int N)
{
    int i = blockIdx.x * 256 + threadIdx.x;
    if (i < N) { dis[i] = 0.f; indeg[i] = 0; }
    if (blockIdx.x == 0 && threadIdx.x < 32) dhist[threadIdx.x] = 0;
}

// ---------------- diagnostic ----------------
__global__ void diag_kernel(float* __restrict__ out, long n, float val)
{
    long i = (long)blockIdx.x * blockDim.x + threadIdx.x;
    if (i < n) out[i] = val;
}

// ---------------- merged tables: convW->bf16, linW->bf16, comb(bf16), BN fold,
//                  atom_emb->bf16 ------------------------------------------
__global__ __launch_bounds__(256) void tables_kernel(
    const float* __restrict__ conv_W, unsigned short* __restrict__ Wb,
    const float* __restrict__ lin_W, unsigned short* __restrict__ linWb,
    const float* __restrict__ bond_emb, unsigned short* __restrict__ comb,
    const float* __restrict__ gamma, const float* __restrict__ beta,
    const float* __restrict__ mean, const float* __restrict__ var,
    float* __restrict__ bnsc, float* __restrict__ bnsh,
    const float* __restrict__ atom_emb, unsigned short* __restrict__ aeb)
{
    int blk = blockIdx.x;
    int tid = threadIdx.x;
    if (blk < 64) {
        int i = blk * 256 + tid;
        Wb[i] = f2bf(conv_W[i]);
    } else if (blk < 128) {
        int i = (blk - 64) * 256 + tid;
        linWb[i] = f2bf(lin_W[i]);
    } else if (blk < 158) {
        int i = (blk - 128) * 2 + (tid >> 7);     // combo row
        int c = tid & 127;
        int a0 = i / 12, a1 = (i % 12) / 2, a2 = i % 2;
        comb[i * HID + c] = f2bf(bond_emb[a0 * HID + c] + bond_emb[(5 + a1) * HID + c]
                               + bond_emb[(11 + a2) * HID + c]);
    } else if (blk == 158) {
        if (tid < HID) {
            float sc = gamma[tid] * rsqrtf(var[tid] + 1e-5f);
            bnsc[tid] = sc;
            bnsh[tid] = beta[tid] - mean[tid] * sc;
        }
    } else {
        int i = (blk - 159) * 256 + tid;
        if (i < AROWS * HID) aeb[i] = f2bf(atom_emb[i]);
    }
}

// ---------------- merged: out-degree (row, into dis) + in-degree (col) -------
__global__ void hist_kernel(const int* __restrict__ ei, float* __restrict__ dis,
                            int* __restrict__ indeg, int E)
{
    for (int e = blockIdx.x * blockDim.x + threadIdx.x; e < E; e += gridDim.x * blockDim.x) {
        atomicAdd(&dis[ei[e]], 1.f);
        atomicAdd(&indeg[ei[E + e]], 1);
    }
}

// ---------------- fdeg (dis -> deg^-0.5) + degree histogram ------------------
__global__ __launch_bounds__(256) void fdh_kernel(
    float* __restrict__ dis, const int* __restrict__ indeg,
    int* __restrict__ dhist, int N)
{
    __shared__ int lh[32];
    int tid = threadIdx.x;
    if (tid < 32) lh[tid] = 0;
    __syncthreads();
    int i = blockIdx.x * 256 + tid;
    if (i < N) {
        dis[i] = rsqrtf(dis[i] + 1.f);
        int d = indeg[i]; if (d > 31) d = 31;
        atomicAdd(&lh[d], 1);
    }
    __syncthreads();
    if (tid < 32 && lh[tid]) atomicAdd(&dhist[tid], lh[tid]);
}

__global__ void dscan_kernel(const int* __restrict__ dhist, int* __restrict__ dcur)
{
    if (threadIdx.x == 0) {
        int s = 0;
        for (int k = 0; k < 32; ++k) { dcur[k] = s; s += dhist[k]; }
    }
}

// ---------------- degree-sorted permutation + inverse ------------------------
__global__ __launch_bounds__(256) void dperm_kernel(
    const int* __restrict__ indeg, int* __restrict__ dcur,
    int* __restrict__ perm, int* __restrict__ invperm, int N)
{
    __shared__ int lh[32];
    __shared__ int gb[32];
    int tid = threadIdx.x;
    if (tid < 32) lh[tid] = 0;
    __syncthreads();
    int n = blockIdx.x * 256 + tid;
    int rank = 0, d = 0;
    if (n < N) {
        d = indeg[n]; if (d > 31) d = 31;
        rank = atomicAdd(&lh[d], 1);        // per-block rank within bucket
    }
    __syncthreads();
    if (tid < 32) gb[tid] = lh[tid] ? atomicAdd(&dcur[tid], lh[tid]) : 0;
    __syncthreads();
    if (n < N) {
        int slot = gb[d] + rank;
        perm[slot] = n;
        invperm[n] = slot;
    }
}

// ---------------- slot-order CSR scan chain ----------------------------------
__global__ __launch_bounds__(256) void sbsum_kernel(
    const int* __restrict__ indeg, const int* __restrict__ perm,
    int* __restrict__ partial, int N)
{
    __shared__ int s[256];
    int tid = threadIdx.x;
    int i = blockIdx.x * 256 + tid;
    s[tid] = (i < N) ? indeg[perm[i]] : 0;
    __syncthreads();
    for (int d = 128; d > 0; d >>= 1) {
        if (tid < d) s[tid] += s[tid + d];
        __syncthreads();
    }
    if (tid == 0) partial[blockIdx.x] = s[0];
}

__global__ __launch_bounds__(256) void sscan1_kernel(
    const int* __restrict__ partial, int* __restrict__ offs,
    int* __restrict__ sptr, int B, int N)
{
    __shared__ int s[256];
    __shared__ int carry_s;
    int tid = threadIdx.x;
    if (tid == 0) carry_s = 0;
    __syncthreads();
    for (int base = 0; base < B; base += 256) {
        int i = base + tid;
        int v = (i < B) ? partial[i] : 0;
        s[tid] = v;
        __syncthreads();
        for (int d = 1; d < 256; d <<= 1) {
            int t = (tid >= d) ? s[tid - d] : 0;
            __syncthreads();
            s[tid] += t;
            __syncthreads();
        }
        int carry = carry_s;
        if (i < B) offs[i] = carry + s[tid] - v;
        __syncthreads();
        if (tid == 0) carry_s = carry + s[255];
        __syncthreads();
    }
    if (tid == 0) sptr[N] = carry_s;
}

__global__ __launch_bounds__(256) void sscan2_kernel(
    const int* __restrict__ indeg, const int* __restrict__ perm,
    const int* __restrict__ offs, int* __restrict__ sptr,
    int* __restrict__ scursor, int N)
{
    __shared__ int s[256];
    int tid = threadIdx.x;
    int i = blockIdx.x * 256 + tid;
    int v = (i < N) ? indeg[perm[i]] : 0;
    s[tid] = v;
    __syncthreads();
    for (int d = 1; d < 256; d <<= 1) {
        int t = (tid >= d) ? s[tid - d] : 0;
        __syncthreads();
        s[tid] += t;
        __syncthreads();
    }
    if (i < N) {
        int ex = offs[blockIdx.x] + s[tid] - v;
        sptr[i] = ex;
        scursor[i] = ex;
    }
}

// ---------------- CSR fill (slot order) {row, ci|bf16(norm)<<16} + gptr ------
__global__ void fillcsr_kernel(const int* __restrict__ ei, const int* __restrict__ attr,
                               const float* __restrict__ dis,
                               const int* __restrict__ invperm,
                               int* __restrict__ scursor,
                               int2* __restrict__ edata, const int* __restrict__ batch,
                               int* __restrict__ gptr, int E, int N, int G)
{
    for (int e = blockIdx.x * blockDim.x + threadIdx.x; e < E; e += gridDim.x * blockDim.x) {
        int r   = ei[e];
        int col = ei[E + e];
        int slot = invperm[col];
        int pos = atomicAdd(&scursor[slot], 1);
        int ci  = attr[e * 3] * 12 + attr[e * 3 + 1] * 2 + attr[e * 3 + 2];
        float nrm = dis[r] * dis[col];
        int2 ed;
        ed.x = r;
        ed.y = ci | ((int)f2bf(nrm) << 16);
        edata[pos] = ed;
    }
    for (int n = blockIdx.x * blockDim.x + threadIdx.x; n < N; n += gridDim.x * blockDim.x) {
        int b = batch[n];
        int bp = (n == 0) ? -1 : batch[n - 1];
        for (int g = bp + 1; g <= b; ++g) gptr[g] = n;
        if (n == N - 1)
            for (int g = b + 1; g <= G; ++g) gptr[g] = N;
    }
}

// ---------------- per-edge accumulate helper ----------------
__device__ __forceinline__ void edge_acc(
    int2 e, const unsigned short* __restrict__ zb,
    const unsigned short* __restrict__ comb, int c, float* acc)
{
    ushort8v z = *reinterpret_cast<const ushort8v*>(zb + (long)e.x * HID + c);
    ushort8v cb = *reinterpret_cast<const ushort8v*>(comb + (e.y & 0xFF) * HID + c);
    float nr = bf2f((unsigned short)(((unsigned)e.y) >> 16));
#pragma unroll
    for (int j = 0; j < 8; ++j)
        acc[j] += fmaxf(bf2f(z[j]) + bf2f(cb[j]), 0.f) * nr;
}

// ---------------- agg: 2 interleaved nodes per 16-lane group -----------------
// slots s and s+16 per group -> 4 z-gathers in flight per thread (2x MLP).
// Degree-sorted slots keep the two trip counts near-equal (minimal predication).
template<bool FIRST>
__global__ __launch_bounds__(256) void agg_kernel(
    const int* __restrict__ perm, const int* __restrict__ sptr,
    const int2* __restrict__ edata, const unsigned short* __restrict__ comb,
    const float* __restrict__ dis, const float* __restrict__ root,
    const float* __restrict__ bnsc, const float* __restrict__ bnsh,
    const unsigned short* __restrict__ zb, unsigned short* __restrict__ hb,
    float fi, int N)
{
    long s0 = (long)blockIdx.x * 32 + (threadIdx.x >> 4);
    if (s0 >= N) return;
    long s1 = s0 + 16;
    bool has1 = (s1 < N);
    int c = (threadIdx.x & 15) * 8;

    long n0 = perm[s0];
    long n1 = has1 ? (long)perm[s1] : n0;
    int jb0 = sptr[s0], je0 = sptr[s0 + 1];
    int jb1 = 0, je1 = 0;
    if (has1) { jb1 = sptr[s1]; je1 = sptr[s1 + 1]; }

    float rt[8], sc[8], sh[8];
#pragma unroll
    for (int j = 0; j < 8; ++j) {
        rt[j] = root[c + j]; sc[j] = bnsc[c + j]; sh[j] = bnsh[c + j];
    }

    ushort8v zv0 = *reinterpret_cast<const ushort8v*>(zb + n0 * HID + c);
    ushort8v zv1 = has1 ? *reinterpret_cast<const ushort8v*>(zb + n1 * HID + c) : zv0;
    ushort8v hv0, hv1;
    if constexpr (!FIRST) {
        hv0 = *reinterpret_cast<const ushort8v*>(hb + n0 * HID + c);
        if (has1) hv1 = *reinterpret_cast<const ushort8v*>(hb + n1 * HID + c);
    }
    float d0 = dis[n0], d1 = dis[n1];
    float rd0 = d0 * d0, rd1 = d1 * d1;

    float acc0[8], acc1[8];
#pragma unroll
    for (int j = 0; j < 8; ++j) {
        acc0[j] = fmaxf(bf2f(zv0[j]) + rt[j], 0.f) * rd0;
        acc1[j] = fmaxf(bf2f(zv1[j]) + rt[j], 0.f) * rd1;
    }

    int j0 = jb0, j1 = jb1;
    // joint main loop: 4 gathers in flight (paired x 2 nodes)
    while (j0 + 1 < je0 && j1 + 1 < je1) {
        int2 ea = edata[j0];
        int2 eb = edata[j0 + 1];
        int2 ec = edata[j1];
        int2 ed = edata[j1 + 1];
        edge_acc(ea, zb, comb, c, acc0);
        edge_acc(eb, zb, comb, c, acc0);
        edge_acc(ec, zb, comb, c, acc1);
        edge_acc(ed, zb, comb, c, acc1);
        j0 += 2; j1 += 2;
    }
    // node0 tail
    for (; j0 + 1 < je0; j0 += 2) {
        int2 ea = edata[j0];
        int2 eb = edata[j0 + 1];
        edge_acc(ea, zb, comb, c, acc0);
        edge_acc(eb, zb, comb, c, acc0);
    }
    if (j0 < je0) edge_acc(edata[j0], zb, comb, c, acc0);
    // node1 tail
    for (; j1 + 1 < je1; j1 += 2) {
        int2 ec = edata[j1];
        int2 ed = edata[j1 + 1];
        edge_acc(ec, zb, comb, c, acc1);
        edge_acc(ed, zb, comb, c, acc1);
    }
    if (j1 < je1) edge_acc(edata[j1], zb, comb, c, acc1);

    ushort8v o0, o1;
#pragma unroll
    for (int j = 0; j < 8; ++j) {
        float t0 = fmaxf(acc0[j], 0.f) * sc[j] + sh[j];
        float t1 = fmaxf(acc1[j], 0.f) * sc[j] + sh[j];
        float h0, h1;
        if constexpr (FIRST) { h0 = t0; h1 = t1; }
        else {
            h0 = fi * bf2f(hv0[j]) + (1.f - fi) * t0;
            h1 = fi * bf2f(hv1[j]) + (1.f - fi) * t1;
        }
        o0[j] = f2bf(h0);
        o1[j] = f2bf(h1);
    }
    *reinterpret_cast<ushort8v*>(hb + n0 * HID + c) = o0;
    if (has1) *reinterpret_cast<ushort8v*>(hb + n1 * HID + c) = o1;
}

// ---------------- shared MFMA epilogue (128-row): hs -> out = hs @ Wb^T + b --
__device__ __forceinline__ void gemm_from_lds(
    unsigned short (*hs)[132], const unsigned short* __restrict__ Wb,
    const float* __restrict__ bias, unsigned short* __restrict__ zb,
    long base, int N, int tid)
{
    int wave = tid >> 6;
    int lane = tid & 63;
    int l15 = lane & 15;
    int q = lane >> 4;
    int rowl0 = wave * 32;

    short8 a[2][4];
#pragma unroll
    for (int mt = 0; mt < 2; ++mt) {
        int rl = rowl0 + mt * 16 + l15;
#pragma unroll
        for (int kb = 0; kb < 4; ++kb)
            a[mt][kb] = *reinterpret_cast<const short8*>(&hs[rl][q * 8 + kb * 32]);
    }

    floatx4 acc[2][8];
#pragma unroll
    for (int mt = 0; mt < 2; ++mt)
#pragma unroll
        for (int nt = 0; nt < 8; ++nt) {
            floatx4 zz = {0.f, 0.f, 0.f, 0.f};
            acc[mt][nt] = zz;
        }

#pragma unroll
    for (int nt = 0; nt < 8; ++nt) {
        const unsigned short* bp = Wb + (nt * 16 + l15) * HID + q * 8;
#pragma unroll
        for (int kb = 0; kb < 4; ++kb) {
            short8 b = *reinterpret_cast<const short8*>(bp + kb * 32);
            acc[0][nt] = __builtin_amdgcn_mfma_f32_16x16x32_bf16(a[0][kb], b, acc[0][nt], 0, 0, 0);
            acc[1][nt] = __builtin_amdgcn_mfma_f32_16x16x32_bf16(a[1][kb], b, acc[1][nt], 0, 0, 0);
        }
    }

    float bi[8];
#pragma unroll
    for (int nt = 0; nt < 8; ++nt) bi[nt] = bias[nt * 16 + l15];

    __syncthreads();
#pragma unroll
    for (int mt = 0; mt < 2; ++mt)
#pragma unroll
        for (int r = 0; r < 4; ++r) {
            int lr = rowl0 + mt * 16 + q * 4 + r;
#pragma unroll
            for (int nt = 0; nt < 8; ++nt)
                hs[lr][l15 + 16 * nt] = f2bf(acc[mt][nt][r] + bi[nt]);
        }
    __syncthreads();

    int tr = tid >> 4;
    int tc = (tid & 15) * 8;
#pragma unroll
    for (int i = 0; i < 8; ++i) {
        int row = i * 16 + tr;
        long gr = base + row;
        if (gr < N) {
            ushort8v v = *reinterpret_cast<const ushort8v*>(&hs[row][tc]);
            *reinterpret_cast<ushort8v*>(zb + gr * HID + tc) = v;
        }
    }
}

// ---------------- fused encode + gemm#1 (128-row tile; proven 76 µs) ---------
__global__ __launch_bounds__(256) void egemm_kernel(
    const int* __restrict__ x, const unsigned short* __restrict__ aeb,
    const unsigned short* __restrict__ Wb, const float* __restrict__ bias,
    unsigned short* __restrict__ zb, int N)
{
    __shared__ unsigned short hs[128][132];
    __shared__ int xs[128 * 9];
    int tid = threadIdx.x;
    long base = (long)blockIdx.x * 128;
    const int OFF[9] = {0, 119, 123, 135, 147, 157, 163, 169, 171};

    int nb = (N - base < 128) ? (int)(N - base) : 128;
    int cnt = nb * 9;
    for (int i = tid; i < cnt; i += 256) xs[i] = x[base * 9 + i];
    __syncthreads();

    int sn = tid >> 4;
    int cc = (tid & 15) * 8;
#pragma unroll 1
    for (int s = 0; s < 8; ++s) {
        int lr = s * 16 + sn;
        ushort8v o;
        if (lr < nb) {
            float acc[8];
#pragma unroll
            for (int j = 0; j < 8; ++j) acc[j] = 0.f;
#pragma unroll
            for (int f = 0; f < 9; ++f) {
                int idx = xs[lr * 9 + f] + OFF[f];
                ushort8v v = *reinterpret_cast<const ushort8v*>(aeb + (long)idx * HID + cc);
#pragma unroll
                for (int j = 0; j < 8; ++j) acc[j] += bf2f(v[j]);
            }
#pragma unroll
            for (int j = 0; j < 8; ++j) o[j] = f2bf(acc[j]);
        } else {
            ushort8v z8 = {0, 0, 0, 0, 0, 0, 0, 0};
            o = z8;
        }
        *reinterpret_cast<ushort8v*>(&hs[lr][cc]) = o;
    }
    __syncthreads();

    gemm_from_lds(hs, Wb, bias, zb, base, N, tid);
}

// ---------------- z = h @ W^T + b  (standalone) ----------------
__global__ __launch_bounds__(256) void gemm_kernel(
    const unsigned short* __restrict__ hb, const unsigned short* __restrict__ Wb,
    const float* __restrict__ bias, unsigned short* __restrict__ zb, int N)
{
    __shared__ unsigned short st[128][132];
    int tid = threadIdx.x;
    int wave = tid >> 6;
    int lane = tid & 63;
    int l15 = lane & 15;
    int q = lane >> 4;
    long base = (long)blockIdx.x * 128;
    long row0 = base + wave * 32;

#pragma unroll
    for (int mt = 0; mt < 2; ++mt) {
        long rl = row0 + mt * 16 + l15;
        if (rl > (long)N - 1) rl = (long)N - 1;
        const unsigned short* ap = hb + rl * HID + q * 8;
        int lrow = wave * 32 + mt * 16 + l15;
#pragma unroll
        for (int kb = 0; kb < 4; ++kb)
            *reinterpret_cast<ushort8v*>(&st[lrow][q * 8 + kb * 32]) =
                *reinterpret_cast<const ushort8v*>(ap + kb * 32);
    }
    __syncthreads();
    gemm_from_lds(st, Wb, bias, zb, base, N, tid);
}

// ---------------- final linear via MFMA ----------------
__global__ __launch_bounds__(256) void linmm_kernel(
    const unsigned short* __restrict__ pb, const unsigned short* __restrict__ Wb,
    const float* __restrict__ bias, float* __restrict__ out, int G)
{
    int wave = threadIdx.x >> 6;
    int lane = threadIdx.x & 63;
    int l15 = lane & 15;
    int q = lane >> 4;
    long row0 = (long)blockIdx.x * 128 + wave * 32;

    short8 a[2][4];
#pragma unroll
    for (int mt = 0; mt < 2; ++mt) {
        long rl = row0 + mt * 16 + l15;
        if (rl > (long)G - 1) rl = (long)G - 1;
        const unsigned short* ap = pb + rl * HID + q * 8;
#pragma unroll
        for (int kb = 0; kb < 4; ++kb)
            a[mt][kb] = *reinterpret_cast<const short8*>(ap + kb * 32);
    }

    floatx4 acc[2][8];
#pragma unroll
    for (int mt = 0; mt < 2; ++mt)
#pragma unroll
        for (int nt = 0; nt < 8; ++nt) {
            floatx4 zz = {0.f, 0.f, 0.f, 0.f};
            acc[mt][nt] = zz;
        }

#pragma unroll
    for (int nt = 0; nt < 8; ++nt) {
        const unsigned short* bp = Wb + (nt * 16 + l15) * HID + q * 8;
#pragma unroll
        for (int kb = 0; kb < 4; ++kb) {
            short8 b = *reinterpret_cast<const short8*>(bp + kb * 32);
            acc[0][nt] = __builtin_amdgcn_mfma_f32_16x16x32_bf16(a[0][kb], b, acc[0][nt], 0, 0, 0);
            acc[1][nt] = __builtin_amdgcn_mfma_f32_16x16x32_bf16(a[1][kb], b, acc[1][nt], 0, 0, 0);
        }
    }

    float bi[8];
#pragma unroll
    for (int nt = 0; nt < 8; ++nt) bi[nt] = bias[nt * 16 + l15];

#pragma unroll
    for (int mt = 0; mt < 2; ++mt)
#pragma unroll
        for (int r = 0; r < 4; ++r) {
            long rr = row0 + mt * 16 + q * 4 + r;
            if (rr < G) {
                float* op = out + rr * HID + l15;
#pragma unroll
                for (int nt = 0; nt < 8; ++nt)
                    op[nt * 16] = acc[mt][nt][r] + bi[nt];
            }
        }
}

// ---------------- mean-pool per graph -> bf16 pooled[G][128] ----------------
__global__ __launch_bounds__(256) void pool_kernel(
    const unsigned short* __restrict__ hb, const int* __restrict__ gptr,
    unsigned short* __restrict__ pb, int G)
{
    int g = blockIdx.x;
    if (g >= G) return;
    int tid = threadIdx.x;
    int sub = tid >> 5;
    int c = (tid & 31) * 4;
    int lo = gptr[g], hi = gptr[g + 1];
    floatx4 s = {0.f, 0.f, 0.f, 0.f};
    for (int n = lo + sub; n < hi; n += 8) {
        ushort4v hv = *reinterpret_cast<const ushort4v*>(hb + (long)n * HID + c);
#pragma unroll
        for (int j = 0; j < 4; ++j) s[j] += bf2f(hv[j]);
    }
    __shared__ float ps[8][HID];
    *reinterpret_cast<floatx4*>(&ps[sub][c]) = s;
    __syncthreads();
    if (tid < HID) {
        float sum = 0.f;
#pragma unroll
        for (int k = 0; k < 8; ++k) sum += ps[k][tid];
        float cnt = (hi > lo) ? (float)(hi - lo) : 1.f;
        pb[(long)g * HID + tid] = f2bf(sum / cnt);
    }
}

extern "C" void kernel_launch(void* const* d_in, const int* in_sizes, int n_in,
                              void* d_out, int out_size, void* d_ws, size_t ws_size,
                              hipStream_t stream)
{
    const int* x          = (const int*)d_in[0];
    const int* ei         = (const int*)d_in[1];
    const int* attr       = (const int*)d_in[2];
    const int* batch      = (const int*)d_in[3];
    const float* atom_emb = (const float*)d_in[4];
    const float* bond_emb = (const float*)d_in[5];
    const float* conv_W   = (const float*)d_in[6];
    const float* conv_b   = (const float*)d_in[7];
    const float* root     = (const float*)d_in[8];
    const float* gamma    = (const float*)d_in[9];
    const float* beta     = (const float*)d_in[10];
    const float* mean     = (const float*)d_in[11];
    const float* var      = (const float*)d_in[12];
    const float* lin_W    = (const float*)d_in[13];
    const float* lin_b    = (const float*)d_in[14];
    float* out = (float*)d_out;

    const int N = in_sizes[0] / 9;
    const int E = in_sizes[1] / 2;
    const int G = out_size / HID;
    const int B = (N + 255) / 256;

    auto al = [](size_t b) { return (b + 255) & ~(size_t)255; };
    const size_t need =
        al((size_t)N * HID * 2) +         // hb
        al((size_t)N * HID * 2) +         // zb
        al((size_t)(N + 1) * 4) +         // sptr
        al((size_t)E * 8) +               // edata (int2)
        al((size_t)N * 4) +               // indeg
        al((size_t)N * 4) +               // perm
        al((size_t)N * 4) +               // invperm
        al((size_t)N * 4) +               // scursor
        al((size_t)2048 * 4) * 2 +        // partial + offs
        al((size_t)(G + 1) * 4) +         // gptr
        al((size_t)(G + 128) * HID * 2) + // pooled bf16 (dis aliases; +tail pad)
        al((size_t)60 * HID * 2) +        // comb (bf16)
        al((size_t)HID * 4) * 2 +         // bnsc + bnsh
        al((size_t)HID * HID * 2) * 2 +   // Wb + linWb
        al((size_t)AROWS * HID * 2) +     // aeb (bf16 atom table)
        al(32 * 4) * 2;                   // dhist + dcur

    if (ws_size < need || B > 2048) {
        float v = (B > 2048) ? 3000.f : (1000.f + (float)(ws_size >> 20));
        long n = (long)out_size;
        diag_kernel<<<(int)((n + 255) / 256), 256, 0, stream>>>(out, n, v);
        return;
    }

    char* wsp = (char*)d_ws;
    size_t used = 0;
    auto alloc = [&](size_t bytes) { char* p = wsp + used; used += al(bytes); return p; };
    unsigned short* hb = (unsigned short*)alloc((size_t)N * HID * 2);
    unsigned short* zb = (unsigned short*)alloc((size_t)N * HID * 2);
    int* sptr     = (int*)alloc((size_t)(N + 1) * 4);
    int2* edata   = (int2*)alloc((size_t)E * 8);
    int* indeg    = (int*)alloc((size_t)N * 4);
    int* perm     = (int*)alloc((size_t)N * 4);
    int* invperm  = (int*)alloc((size_t)N * 4);
    int* scursor  = (int*)alloc((size_t)N * 4);
    int* partial  = (int*)alloc((size_t)2048 * 4);
    int* offs     = (int*)alloc((size_t)2048 * 4);
    int* gptr     = (int*)alloc((size_t)(G + 1) * 4);
    unsigned short* pb = (unsigned short*)alloc((size_t)(G + 128) * HID * 2);
    float* dis    = (float*)pb;               // alias: dis dead before pool writes pb
    unsigned short* comb = (unsigned short*)alloc((size_t)60 * HID * 2);
    float* bnsc   = (float*)alloc((size_t)HID * 4);
    float* bnsh   = (float*)alloc((size_t)HID * 4);
    unsigned short* Wb    = (unsigned short*)alloc((size_t)HID * HID * 2);
    unsigned short* linWb = (unsigned short*)alloc((size_t)HID * HID * 2);
    unsigned short* aeb   = (unsigned short*)alloc((size_t)AROWS * HID * 2);
    int* dhist    = (int*)alloc(32 * 4);
    int* dcur     = (int*)alloc(32 * 4);

    // ---- prologue (10 launches) ----
    fillrd_kernel<<<B, 256, 0, stream>>>(dis, indeg, dhist, N);
    tables_kernel<<<246, 256, 0, stream>>>(conv_W, Wb, lin_W, linWb, bond_emb, comb,
                                           gamma, beta, mean, var, bnsc, bnsh,
                                           atom_emb, aeb);
    hist_kernel<<<1024, 256, 0, stream>>>(ei, dis, indeg, E);
    fdh_kernel<<<B, 256, 0, stream>>>(dis, indeg, dhist, N);
    dscan_kernel<<<1, 64, 0, stream>>>(dhist, dcur);
    dperm_kernel<<<B, 256, 0, stream>>>(indeg, dcur, perm, invperm, N);
    sbsum_kernel<<<B, 256, 0, stream>>>(indeg, perm, partial, N);
    sscan1_kernel<<<1, 256, 0, stream>>>(partial, offs, sptr, B, N);
    sscan2_kernel<<<B, 256, 0, stream>>>(indeg, perm, offs, sptr, scursor, N);
    fillcsr_kernel<<<1024, 256, 0, stream>>>(ei, attr, dis, invperm, scursor, edata,
                                             batch, gptr, E, N, G);

    // ---- loop (i=1 is identity, skipped; fis = {0,2,3,4}) ----
    const int gemm_blocks = (N + 127) / 128;
    const int agg_blocks  = (N + 31) / 32;
    egemm_kernel<<<gemm_blocks, 256, 0, stream>>>(x, aeb, Wb, conv_b, zb, N);
    agg_kernel<true ><<<agg_blocks, 256, 0, stream>>>(perm, sptr, edata, comb, dis,
            root, bnsc, bnsh, zb, hb, 0.f, N);
    const float fis[3] = {2.f, 3.f, 4.f};
    for (int t = 0; t < 3; ++t) {
        gemm_kernel<<<gemm_blocks, 256, 0, stream>>>(hb, Wb, conv_b, zb, N);
        agg_kernel<false><<<agg_blocks, 256, 0, stream>>>(perm, sptr, edata, comb, dis,
                root, bnsc, bnsh, zb, hb, fis[t], N);
    }

    // ---- mean-pool (bf16) + MFMA final linear (fp32 out) ----
    pool_kernel<<<G, 256, 0, stream>>>(hb, gptr, pb, G);
    linmm_kernel<<<(G + 127) / 128, 256, 0, stream>>>(pb, linWb, lin_b, out, G);
}

// Round 7
// 660.345 us; speedup vs baseline: 1.2080x; 1.1004x over previous
//
#include <hip/hip_runtime.h>

#define HID 128
#define AROWS 173   // sum(ATOM_DIMS) = 173 (offsets end at 171, last dim = 2)

typedef __attribute__((ext_vector_type(8))) short short8;
typedef __attribute__((ext_vector_type(8))) unsigned short ushort8v;
typedef __attribute__((ext_vector_type(4))) float floatx4;
typedef __attribute__((ext_vector_type(4))) unsigned short ushort4v;

__device__ __forceinline__ unsigned short f2bf(float f) {
    unsigned u = __builtin_bit_cast(unsigned, f);
    u += 0x7FFF + ((u >> 16) & 1);           // RNE
    return (unsigned short)(u >> 16);
}
__device__ __forceinline__ float bf2f(unsigned short s) {
    unsigned u = ((unsigned)s) << 16;
    return __builtin_bit_cast(float, u);
}

// ---------------- merged fill: dis (deg accumulator) + indeg ----------------
__global__ void fillrd_kernel(float* __restrict__ dis, int* __restrict__ indeg, int N)
{
    int i = blockIdx.x * 256 + threadIdx.x;
    if (i < N) { dis[i] = 0.f; indeg[i] = 0; }
}

// ---------------- diagnostic ----------------
__global__ void diag_kernel(float* __restrict__ out, long n, float val)
{
    long i = (long)blockIdx.x * blockDim.x + threadIdx.x;
    if (i < n) out[i] = val;
}

// ---------------- merged tables: convW->bf16, linW->bf16, comb(bf16), BN fold
// blocks 0..63: conv_W cvt | 64..127: lin_W cvt | 128..157: comb | 158: BN
__global__ __launch_bounds__(256) void tables_kernel(
    const float* __restrict__ conv_W, unsigned short* __restrict__ Wb,
    const float* __restrict__ lin_W, unsigned short* __restrict__ linWb,
    const float* __restrict__ bond_emb, unsigned short* __restrict__ comb,
    const float* __restrict__ gamma, const float* __restrict__ beta,
    const float* __restrict__ mean, const float* __restrict__ var,
    float* __restrict__ bnsc, float* __restrict__ bnsh)
{
    int blk = blockIdx.x;
    int tid = threadIdx.x;
    if (blk < 64) {
        int i = blk * 256 + tid;
        Wb[i] = f2bf(conv_W[i]);
    } else if (blk < 128) {
        int i = (blk - 64) * 256 + tid;
        linWb[i] = f2bf(lin_W[i]);
    } else if (blk < 158) {
        int i = (blk - 128) * 2 + (tid >> 7);     // combo row
        int c = tid & 127;
        int a0 = i / 12, a1 = (i % 12) / 2, a2 = i % 2;
        comb[i * HID + c] = f2bf(bond_emb[a0 * HID + c] + bond_emb[(5 + a1) * HID + c]
                               + bond_emb[(11 + a2) * HID + c]);
    } else if (tid < HID) {
        float sc = gamma[tid] * rsqrtf(var[tid] + 1e-5f);
        bnsc[tid] = sc;
        bnsh[tid] = beta[tid] - mean[tid] * sc;
    }
}

// ---------------- EW = atom_emb @ conv_W^T -> bf16 [173][128] ----------------
// Folds AtomEncoder + gemm#1: z[n] = sum_f EW[x[n,f]+OFF_f] + conv_b.
// fp32 dot (more precise than the old bf16-h0 + bf16 MFMA path).
__global__ __launch_bounds__(128) void ewk_kernel(
    const float* __restrict__ atom_emb, const float* __restrict__ conv_W,
    unsigned short* __restrict__ EWb)
{
    int r = blockIdx.x;           // 0..172
    int c = threadIdx.x;          // 0..127
    const float* er = atom_emb + (long)r * HID;   // broadcast across block
    const float* wr = conv_W + (long)c * HID;
    float acc = 0.f;
#pragma unroll 4
    for (int k = 0; k < HID; k += 4) {
        floatx4 e4 = *reinterpret_cast<const floatx4*>(er + k);
        floatx4 w4 = *reinterpret_cast<const floatx4*>(wr + k);
        acc += e4[0] * w4[0] + e4[1] * w4[1] + e4[2] * w4[2] + e4[3] * w4[3];
    }
    EWb[(long)r * HID + c] = f2bf(acc);
}

// ---------------- merged: out-degree (row, into dis) + in-degree (col) -------
__global__ void hist_kernel(const int* __restrict__ ei, float* __restrict__ dis,
                            int* __restrict__ indeg, int E)
{
    for (int e = blockIdx.x * blockDim.x + threadIdx.x; e < E; e += gridDim.x * blockDim.x) {
        atomicAdd(&dis[ei[e]], 1.f);
        atomicAdd(&indeg[ei[E + e]], 1);
    }
}

// ---------------- CSR scan chain (node order) + fdeg fold --------------------
__global__ __launch_bounds__(256) void bsum_kernel(
    const int* __restrict__ indeg, int* __restrict__ partial,
    float* __restrict__ dis, int N)
{
    __shared__ int s[256];
    int tid = threadIdx.x;
    int i = blockIdx.x * 256 + tid;
    int v = (i < N) ? indeg[i] : 0;
    s[tid] = v;
    if (i < N) dis[i] = rsqrtf(dis[i] + 1.f);     // fdeg folded (hist complete)
    __syncthreads();
    for (int d = 128; d > 0; d >>= 1) {
        if (tid < d) s[tid] += s[tid + d];
        __syncthreads();
    }
    if (tid == 0) partial[blockIdx.x] = s[0];
}

__global__ __launch_bounds__(256) void scan1_kernel(
    const int* __restrict__ partial, int* __restrict__ offs,
    int* __restrict__ ptr, int B, int N)
{
    __shared__ int s[256];
    __shared__ int carry_s;
    int tid = threadIdx.x;
    if (tid == 0) carry_s = 0;
    __syncthreads();
    for (int base = 0; base < B; base += 256) {
        int i = base + tid;
        int v = (i < B) ? partial[i] : 0;
        s[tid] = v;
        __syncthreads();
        for (int d = 1; d < 256; d <<= 1) {
            int t = (tid >= d) ? s[tid - d] : 0;
            __syncthreads();
            s[tid] += t;
            __syncthreads();
        }
        int carry = carry_s;
        if (i < B) offs[i] = carry + s[tid] - v;
        __syncthreads();
        if (tid == 0) carry_s = carry + s[255];
        __syncthreads();
    }
    if (tid == 0) ptr[N] = carry_s;
}

// in-place safe: cursor may alias indeg (read-before-write per element)
__global__ __launch_bounds__(256) void scan2_kernel(
    const int* __restrict__ indeg, const int* __restrict__ offs,
    int* __restrict__ ptr, int* __restrict__ cursor, int N)
{
    __shared__ int s[256];
    int tid = threadIdx.x;
    int i = blockIdx.x * 256 + tid;
    int v = (i < N) ? indeg[i] : 0;
    s[tid] = v;
    __syncthreads();
    for (int d = 1; d < 256; d <<= 1) {
        int t = (tid >= d) ? s[tid - d] : 0;
        __syncthreads();
        s[tid] += t;
        __syncthreads();
    }
    if (i < N) {
        int ex = offs[blockIdx.x] + s[tid] - v;
        ptr[i] = ex;
        cursor[i] = ex;
    }
}

// ---------------- CSR fill {row, ci|bf16(norm)<<16} + (folded) gptr ----------
__global__ void fillcsr_kernel(const int* __restrict__ ei, const int* __restrict__ attr,
                               const float* __restrict__ dis, int* __restrict__ cursor,
                               int2* __restrict__ edata, const int* __restrict__ batch,
                               int* __restrict__ gptr, int E, int N, int G)
{
    for (int e = blockIdx.x * blockDim.x + threadIdx.x; e < E; e += gridDim.x * blockDim.x) {
        int r   = ei[e];
        int col = ei[E + e];
        int pos = atomicAdd(&cursor[col], 1);
        int ci  = attr[e * 3] * 12 + attr[e * 3 + 1] * 2 + attr[e * 3 + 2];
        float nrm = dis[r] * dis[col];
        int2 ed;
        ed.x = r;
        ed.y = ci | ((int)f2bf(nrm) << 16);
        edata[pos] = ed;
    }
    for (int n = blockIdx.x * blockDim.x + threadIdx.x; n < N; n += gridDim.x * blockDim.x) {
        int b = batch[n];
        int bp = (n == 0) ? -1 : batch[n - 1];
        for (int g = bp + 1; g <= b; ++g) gptr[g] = n;
        if (n == N - 1)
            for (int g = b + 1; g <= G; ++g) gptr[g] = N;
    }
}

// ---------------- encode: z = sum_f EW[idx_f] + b (replaces egemm) -----------
// Pure gather-sum from a 44 KB L1/L2-hot table; no LDS / MFMA / barriers.
__global__ __launch_bounds__(256) void enc_kernel(
    const int* __restrict__ x, const unsigned short* __restrict__ EWb,
    const float* __restrict__ bias, unsigned short* __restrict__ zb, int N)
{
    long n = (long)blockIdx.x * 16 + (threadIdx.x >> 4);
    if (n >= N) return;
    int c = (threadIdx.x & 15) * 8;
    const int OFF[9] = {0, 119, 123, 135, 147, 157, 163, 169, 171};

    float acc[8];
#pragma unroll
    for (int j = 0; j < 8; ++j) acc[j] = bias[c + j];

#pragma unroll
    for (int f = 0; f < 9; ++f) {
        int idx = x[n * 9 + f] + OFF[f];              // 16-lane broadcast load
        ushort8v v = *reinterpret_cast<const ushort8v*>(EWb + (long)idx * HID + c);
#pragma unroll
        for (int j = 0; j < 8; ++j) acc[j] += bf2f(v[j]);
    }

    ushort8v o;
#pragma unroll
    for (int j = 0; j < 8; ++j) o[j] = f2bf(acc[j]);
    *reinterpret_cast<ushort8v*>(zb + n * HID + c) = o;
}

// ---------------- agg: one node per 16-lane group (node-order CSR) -----------
template<bool FIRST>
__global__ __launch_bounds__(256) void agg_kernel(
    const int* __restrict__ ptr, const int2* __restrict__ edata,
    const unsigned short* __restrict__ comb, const float* __restrict__ dis,
    const float* __restrict__ root, const float* __restrict__ bnsc,
    const float* __restrict__ bnsh, const unsigned short* __restrict__ zb,
    unsigned short* __restrict__ hb, float fi, int N)
{
    long n = (long)blockIdx.x * 16 + (threadIdx.x >> 4);
    if (n >= N) return;
    int c = (threadIdx.x & 15) * 8;

    ushort8v zv = *reinterpret_cast<const ushort8v*>(zb + n * HID + c);
    ushort8v hv;
    if constexpr (!FIRST) hv = *reinterpret_cast<const ushort8v*>(hb + n * HID + c);
    float di = dis[n];
    float rd = di * di;                       // 1/deg
    float acc[8];
#pragma unroll
    for (int j = 0; j < 8; ++j) acc[j] = fmaxf(bf2f(zv[j]) + root[c + j], 0.f) * rd;

    int jb = ptr[n], je = ptr[n + 1];
    int j2 = jb;
    for (; j2 + 1 < je; j2 += 2) {            // paired: 2 gathers in flight
        int2 e0 = edata[j2];
        int2 e1 = edata[j2 + 1];
        ushort8v z0 = *reinterpret_cast<const ushort8v*>(zb + (long)e0.x * HID + c);
        ushort8v z1 = *reinterpret_cast<const ushort8v*>(zb + (long)e1.x * HID + c);
        ushort8v c0 = *reinterpret_cast<const ushort8v*>(comb + (e0.y & 0xFF) * HID + c);
        ushort8v c1 = *reinterpret_cast<const ushort8v*>(comb + (e1.y & 0xFF) * HID + c);
        float n0 = bf2f((unsigned short)(((unsigned)e0.y) >> 16));
        float n1 = bf2f((unsigned short)(((unsigned)e1.y) >> 16));
#pragma unroll
        for (int j = 0; j < 8; ++j) {
            acc[j] += fmaxf(bf2f(z0[j]) + bf2f(c0[j]), 0.f) * n0;
            acc[j] += fmaxf(bf2f(z1[j]) + bf2f(c1[j]), 0.f) * n1;
        }
    }
    if (j2 < je) {
        int2 e0 = edata[j2];
        ushort8v z0 = *reinterpret_cast<const ushort8v*>(zb + (long)e0.x * HID + c);
        ushort8v c0 = *reinterpret_cast<const ushort8v*>(comb + (e0.y & 0xFF) * HID + c);
        float n0 = bf2f((unsigned short)(((unsigned)e0.y) >> 16));
#pragma unroll
        for (int j = 0; j < 8; ++j)
            acc[j] += fmaxf(bf2f(z0[j]) + bf2f(c0[j]), 0.f) * n0;
    }

    ushort8v o;
#pragma unroll
    for (int j = 0; j < 8; ++j) {
        float t = fmaxf(acc[j], 0.f) * bnsc[c + j] + bnsh[c + j];
        float h;
        if constexpr (FIRST) h = t;
        else h = fi * bf2f(hv[j]) + (1.f - fi) * t;
        o[j] = f2bf(h);
    }
    *reinterpret_cast<ushort8v*>(hb + n * HID + c) = o;
}

// ---------------- shared MFMA epilogue (128-row): hs -> out = hs @ Wb^T + b --
__device__ __forceinline__ void gemm_from_lds(
    unsigned short (*hs)[132], const unsigned short* __restrict__ Wb,
    const float* __restrict__ bias, unsigned short* __restrict__ zb,
    long base, int N, int tid)
{
    int wave = tid >> 6;
    int lane = tid & 63;
    int l15 = lane & 15;
    int q = lane >> 4;
    int rowl0 = wave * 32;

    short8 a[2][4];
#pragma unroll
    for (int mt = 0; mt < 2; ++mt) {
        int rl = rowl0 + mt * 16 + l15;
#pragma unroll
        for (int kb = 0; kb < 4; ++kb)
            a[mt][kb] = *reinterpret_cast<const short8*>(&hs[rl][q * 8 + kb * 32]);
    }

    floatx4 acc[2][8];
#pragma unroll
    for (int mt = 0; mt < 2; ++mt)
#pragma unroll
        for (int nt = 0; nt < 8; ++nt) {
            floatx4 zz = {0.f, 0.f, 0.f, 0.f};
            acc[mt][nt] = zz;
        }

#pragma unroll
    for (int nt = 0; nt < 8; ++nt) {
        const unsigned short* bp = Wb + (nt * 16 + l15) * HID + q * 8;
#pragma unroll
        for (int kb = 0; kb < 4; ++kb) {
            short8 b = *reinterpret_cast<const short8*>(bp + kb * 32);
            acc[0][nt] = __builtin_amdgcn_mfma_f32_16x16x32_bf16(a[0][kb], b, acc[0][nt], 0, 0, 0);
            acc[1][nt] = __builtin_amdgcn_mfma_f32_16x16x32_bf16(a[1][kb], b, acc[1][nt], 0, 0, 0);
        }
    }

    float bi[8];
#pragma unroll
    for (int nt = 0; nt < 8; ++nt) bi[nt] = bias[nt * 16 + l15];

    __syncthreads();
#pragma unroll
    for (int mt = 0; mt < 2; ++mt)
#pragma unroll
        for (int r = 0; r < 4; ++r) {
            int lr = rowl0 + mt * 16 + q * 4 + r;
#pragma unroll
            for (int nt = 0; nt < 8; ++nt)
                hs[lr][l15 + 16 * nt] = f2bf(acc[mt][nt][r] + bi[nt]);
        }
    __syncthreads();

    int tr = tid >> 4;
    int tc = (tid & 15) * 8;
#pragma unroll
    for (int i = 0; i < 8; ++i) {
        int row = i * 16 + tr;
        long gr = base + row;
        if (gr < N) {
            ushort8v v = *reinterpret_cast<const ushort8v*>(&hs[row][tc]);
            *reinterpret_cast<ushort8v*>(zb + gr * HID + tc) = v;
        }
    }
}

// ---------------- z = h @ W^T + b  (standalone) ----------------
__global__ __launch_bounds__(256) void gemm_kernel(
    const unsigned short* __restrict__ hb, const unsigned short* __restrict__ Wb,
    const float* __restrict__ bias, unsigned short* __restrict__ zb, int N)
{
    __shared__ unsigned short st[128][132];
    int tid = threadIdx.x;
    int wave = tid >> 6;
    int lane = tid & 63;
    int l15 = lane & 15;
    int q = lane >> 4;
    long base = (long)blockIdx.x * 128;
    long row0 = base + wave * 32;

#pragma unroll
    for (int mt = 0; mt < 2; ++mt) {
        long rl = row0 + mt * 16 + l15;
        if (rl > (long)N - 1) rl = (long)N - 1;
        const unsigned short* ap = hb + rl * HID + q * 8;
        int lrow = wave * 32 + mt * 16 + l15;
#pragma unroll
        for (int kb = 0; kb < 4; ++kb)
            *reinterpret_cast<ushort8v*>(&st[lrow][q * 8 + kb * 32]) =
                *reinterpret_cast<const ushort8v*>(ap + kb * 32);
    }
    __syncthreads();
    gemm_from_lds(st, Wb, bias, zb, base, N, tid);
}

// ---------------- final linear via MFMA ----------------
__global__ __launch_bounds__(256) void linmm_kernel(
    const unsigned short* __restrict__ pb, const unsigned short* __restrict__ Wb,
    const float* __restrict__ bias, float* __restrict__ out, int G)
{
    int wave = threadIdx.x >> 6;
    int lane = threadIdx.x & 63;
    int l15 = lane & 15;
    int q = lane >> 4;
    long row0 = (long)blockIdx.x * 128 + wave * 32;

    short8 a[2][4];
#pragma unroll
    for (int mt = 0; mt < 2; ++mt) {
        long rl = row0 + mt * 16 + l15;
        if (rl > (long)G - 1) rl = (long)G - 1;
        const unsigned short* ap = pb + rl * HID + q * 8;
#pragma unroll
        for (int kb = 0; kb < 4; ++kb)
            a[mt][kb] = *reinterpret_cast<const short8*>(ap + kb * 32);
    }

    floatx4 acc[2][8];
#pragma unroll
    for (int mt = 0; mt < 2; ++mt)
#pragma unroll
        for (int nt = 0; nt < 8; ++nt) {
            floatx4 zz = {0.f, 0.f, 0.f, 0.f};
            acc[mt][nt] = zz;
        }

#pragma unroll
    for (int nt = 0; nt < 8; ++nt) {
        const unsigned short* bp = Wb + (nt * 16 + l15) * HID + q * 8;
#pragma unroll
        for (int kb = 0; kb < 4; ++kb) {
            short8 b = *reinterpret_cast<const short8*>(bp + kb * 32);
            acc[0][nt] = __builtin_amdgcn_mfma_f32_16x16x32_bf16(a[0][kb], b, acc[0][nt], 0, 0, 0);
            acc[1][nt] = __builtin_amdgcn_mfma_f32_16x16x32_bf16(a[1][kb], b, acc[1][nt], 0, 0, 0);
        }
    }

    float bi[8];
#pragma unroll
    for (int nt = 0; nt < 8; ++nt) bi[nt] = bias[nt * 16 + l15];

#pragma unroll
    for (int mt = 0; mt < 2; ++mt)
#pragma unroll
        for (int r = 0; r < 4; ++r) {
            long rr = row0 + mt * 16 + q * 4 + r;
            if (rr < G) {
                float* op = out + rr * HID + l15;
#pragma unroll
                for (int nt = 0; nt < 8; ++nt)
                    op[nt * 16] = acc[mt][nt][r] + bi[nt];
            }
        }
}

// ---------------- mean-pool per graph -> bf16 pooled[G][128] ----------------
__global__ __launch_bounds__(256) void pool_kernel(
    const unsigned short* __restrict__ hb, const int* __restrict__ gptr,
    unsigned short* __restrict__ pb, int G)
{
    int g = blockIdx.x;
    if (g >= G) return;
    int tid = threadIdx.x;
    int sub = tid >> 5;
    int c = (tid & 31) * 4;
    int lo = gptr[g], hi = gptr[g + 1];
    floatx4 s = {0.f, 0.f, 0.f, 0.f};
    for (int n = lo + sub; n < hi; n += 8) {
        ushort4v hv = *reinterpret_cast<const ushort4v*>(hb + (long)n * HID + c);
#pragma unroll
        for (int j = 0; j < 4; ++j) s[j] += bf2f(hv[j]);
    }
    __shared__ float ps[8][HID];
    *reinterpret_cast<floatx4*>(&ps[sub][c]) = s;
    __syncthreads();
    if (tid < HID) {
        float sum = 0.f;
#pragma unroll
        for (int k = 0; k < 8; ++k) sum += ps[k][tid];
        float cnt = (hi > lo) ? (float)(hi - lo) : 1.f;
        pb[(long)g * HID + tid] = f2bf(sum / cnt);
    }
}

extern "C" void kernel_launch(void* const* d_in, const int* in_sizes, int n_in,
                              void* d_out, int out_size, void* d_ws, size_t ws_size,
                              hipStream_t stream)
{
    const int* x          = (const int*)d_in[0];
    const int* ei         = (const int*)d_in[1];
    const int* attr       = (const int*)d_in[2];
    const int* batch      = (const int*)d_in[3];
    const float* atom_emb = (const float*)d_in[4];
    const float* bond_emb = (const float*)d_in[5];
    const float* conv_W   = (const float*)d_in[6];
    const float* conv_b   = (const float*)d_in[7];
    const float* root     = (const float*)d_in[8];
    const float* gamma    = (const float*)d_in[9];
    const float* beta     = (const float*)d_in[10];
    const float* mean     = (const float*)d_in[11];
    const float* var      = (const float*)d_in[12];
    const float* lin_W    = (const float*)d_in[13];
    const float* lin_b    = (const float*)d_in[14];
    float* out = (float*)d_out;

    const int N = in_sizes[0] / 9;
    const int E = in_sizes[1] / 2;
    const int G = out_size / HID;
    const int B = (N + 255) / 256;

    auto al = [](size_t b) { return (b + 255) & ~(size_t)255; };
    const size_t need =
        al((size_t)N * HID * 2) +         // hb
        al((size_t)N * HID * 2) +         // zb
        al((size_t)(N + 1) * 4) +         // ptr
        al((size_t)E * 8) +               // edata (int2)
        al((size_t)N * 4) +               // indeg (= cursor)
        al((size_t)2048 * 4) * 2 +        // partial + offs
        al((size_t)(G + 1) * 4) +         // gptr
        al((size_t)(G + 128) * HID * 2) + // pooled bf16 (dis aliases; +tail pad)
        al((size_t)60 * HID * 2) +        // comb (bf16)
        al((size_t)HID * 4) * 2 +         // bnsc + bnsh
        al((size_t)HID * HID * 2) * 2 +   // Wb + linWb
        al((size_t)AROWS * HID * 2);      // EWb (bf16 atom_emb @ conv_W^T)

    if (ws_size < need || B > 2048) {
        float v = (B > 2048) ? 3000.f : (1000.f + (float)(ws_size >> 20));
        long n = (long)out_size;
        diag_kernel<<<(int)((n + 255) / 256), 256, 0, stream>>>(out, n, v);
        return;
    }

    char* wsp = (char*)d_ws;
    size_t used = 0;
    auto alloc = [&](size_t bytes) { char* p = wsp + used; used += al(bytes); return p; };
    unsigned short* hb = (unsigned short*)alloc((size_t)N * HID * 2);
    unsigned short* zb = (unsigned short*)alloc((size_t)N * HID * 2);
    int* ptr      = (int*)alloc((size_t)(N + 1) * 4);
    int2* edata   = (int2*)alloc((size_t)E * 8);
    int* indeg    = (int*)alloc((size_t)N * 4);
    int* cursor   = indeg;                    // in-place scan (element-wise safe)
    int* partial  = (int*)alloc((size_t)2048 * 4);
    int* offs     = (int*)alloc((size_t)2048 * 4);
    int* gptr     = (int*)alloc((size_t)(G + 1) * 4);
    unsigned short* pb = (unsigned short*)alloc((size_t)(G + 128) * HID * 2);
    float* dis    = (float*)pb;               // alias: dis dead before pool writes pb
    unsigned short* comb = (unsigned short*)alloc((size_t)60 * HID * 2);
    float* bnsc   = (float*)alloc((size_t)HID * 4);
    float* bnsh   = (float*)alloc((size_t)HID * 4);
    unsigned short* Wb    = (unsigned short*)alloc((size_t)HID * HID * 2);
    unsigned short* linWb = (unsigned short*)alloc((size_t)HID * HID * 2);
    unsigned short* EWb   = (unsigned short*)alloc((size_t)AROWS * HID * 2);

    // ---- prologue (8 launches) ----
    fillrd_kernel<<<B, 256, 0, stream>>>(dis, indeg, N);
    tables_kernel<<<159, 256, 0, stream>>>(conv_W, Wb, lin_W, linWb, bond_emb, comb,
                                           gamma, beta, mean, var, bnsc, bnsh);
    ewk_kernel<<<AROWS, 128, 0, stream>>>(atom_emb, conv_W, EWb);
    hist_kernel<<<1024, 256, 0, stream>>>(ei, dis, indeg, E);
    bsum_kernel<<<B, 256, 0, stream>>>(indeg, partial, dis, N);
    scan1_kernel<<<1, 256, 0, stream>>>(partial, offs, ptr, B, N);
    scan2_kernel<<<B, 256, 0, stream>>>(indeg, offs, ptr, cursor, N);
    fillcsr_kernel<<<1024, 256, 0, stream>>>(ei, attr, dis, cursor, edata,
                                             batch, gptr, E, N, G);

    // ---- loop (i=1 is identity, skipped; fis = {0,2,3,4}) ----
    const int gemm_blocks = (N + 127) / 128;
    const int node_blocks = (N + 15) / 16;
    enc_kernel<<<node_blocks, 256, 0, stream>>>(x, EWb, conv_b, zb, N);
    agg_kernel<true ><<<node_blocks, 256, 0, stream>>>(ptr, edata, comb, dis,
            root, bnsc, bnsh, zb, hb, 0.f, N);
    const float fis[3] = {2.f, 3.f, 4.f};
    for (int t = 0; t < 3; ++t) {
        gemm_kernel<<<gemm_blocks, 256, 0, stream>>>(hb, Wb, conv_b, zb, N);
        agg_kernel<false><<<node_blocks, 256, 0, stream>>>(ptr, edata, comb, dis,
                root, bnsc, bnsh, zb, hb, fis[t], N);
    }

    // ---- mean-pool (bf16) + MFMA final linear (fp32 out) ----
    pool_kernel<<<G, 256, 0, stream>>>(hb, gptr, pb, G);
    linmm_kernel<<<(G + 127) / 128, 256, 0, stream>>>(pb, linWb, lin_b, out, G);
}